// Round 1
// baseline (8255.631 us; speedup 1.0000x reference)
//
#include <hip/hip_runtime.h>
#include <cstdint>
#include <cmath>

#define DIMD  1024
#define NEXP  8
#define HIDN  4096
#define BATCH 4
#define SEQ   2048
#define CAPC  513                 // int(2048*2.0/8)+1
#define MROWS (BATCH * CAPC)      // 2052

#define BM 128
#define BN 64
#define BK 16

// ---------------- router: scores_t [B][E][S] = softmax over E ----------------
__global__ __launch_bounds__(64)
void router_kernel(const float* __restrict__ x, const float* __restrict__ rw,
                   float* __restrict__ scores) {
    int token = blockIdx.x;            // b*SEQ + s
    int lane  = threadIdx.x;           // 0..63
    const float4* xr = reinterpret_cast<const float4*>(x + (size_t)token * DIMD);
    float4 xv[4];
#pragma unroll
    for (int j = 0; j < 4; ++j) xv[j] = xr[lane * 4 + j];

    float acc[NEXP];
#pragma unroll
    for (int e = 0; e < NEXP; ++e) {
        const float4* wr = reinterpret_cast<const float4*>(rw + (size_t)e * DIMD);
        float a = 0.f;
#pragma unroll
        for (int j = 0; j < 4; ++j) {
            float4 wv = wr[lane * 4 + j];
            a += xv[j].x * wv.x; a += xv[j].y * wv.y;
            a += xv[j].z * wv.z; a += xv[j].w * wv.w;
        }
#pragma unroll
        for (int off = 32; off > 0; off >>= 1) a += __shfl_xor(a, off);
        acc[e] = a;                    // all lanes hold the full dot
    }
    // softmax over experts
    float m = acc[0];
#pragma unroll
    for (int e = 1; e < NEXP; ++e) m = fmaxf(m, acc[e]);
    float s = 0.f;
#pragma unroll
    for (int e = 0; e < NEXP; ++e) { acc[e] = expf(acc[e] - m); s += acc[e]; }
    float inv = 1.f / s;

    if (lane == 0) {
        int b = token >> 11;           // /SEQ
        int t = token & (SEQ - 1);
#pragma unroll
        for (int e = 0; e < NEXP; ++e)
            scores[((size_t)(b * NEXP + e)) * SEQ + t] = acc[e] * inv;
    }
}

// ---------------- expert-choice top-k via exact rank (stable, desc) ----------
__global__ __launch_bounds__(256)
void topk_kernel(const float* __restrict__ scores, int* __restrict__ sel,
                 float* __restrict__ gate) {
    int be = blockIdx.x;               // b*NEXP + e
    const float* sc = scores + (size_t)be * SEQ;
    __shared__ float s_sc[SEQ];
    for (int i = threadIdx.x; i < SEQ; i += 256) s_sc[i] = sc[i];
    __syncthreads();
    for (int i = threadIdx.x; i < SEQ; i += 256) {
        float v = s_sc[i];
        int rank = 0;
        for (int j = 0; j < SEQ; ++j) {
            float u = s_sc[j];
            rank += (u > v) || (u == v && j < i);
        }
        if (rank < CAPC) {
            sel [(size_t)be * CAPC + rank] = i;
            gate[(size_t)be * CAPC + rank] = v;
        }
    }
}

// ---------------- GEMM1: h = gelu(gather(x) @ w1[e] + b1[e]) -----------------
// M=2052 (gathered rows), N=4096, K=1024. 128x64 tile, 128 thr, 8x8/thread.
__global__ __launch_bounds__(128)
void gemm1_kernel(const float* __restrict__ x, const float* __restrict__ w1e,
                  const float* __restrict__ b1e, const int* __restrict__ sel,
                  float* __restrict__ h, int e) {
    int bm = blockIdx.x * BM;
    int bn = blockIdx.y * BN;
    int tid = threadIdx.x;
    int ty = tid >> 3, tx = tid & 7;

    __shared__ float As[BK][BM + 4];   // k-major, pad 4 keeps rows 16B-aligned
    __shared__ float Bs[BK][BN];

    // per-thread gathered row (thread t owns tile row t since BM==blockDim)
    int r = bm + tid;
    int xoff = 0;
    if (r < MROWS) {
        int b = r / CAPC, c = r - b * CAPC;
        int tok = sel[(b * NEXP + e) * CAPC + c];
        xoff = (b * SEQ + tok) * DIMD;
    }

    float acc[8][8];
#pragma unroll
    for (int i = 0; i < 8; ++i)
#pragma unroll
        for (int j = 0; j < 8; ++j) acc[i][j] = 0.f;

    int bk  = tid >> 3;                // 0..15
    int bnq = (tid & 7) * 8;           // 0..56

    for (int k0 = 0; k0 < DIMD; k0 += BK) {
        float4 av[4];
#pragma unroll
        for (int q = 0; q < 4; ++q)
            av[q] = *reinterpret_cast<const float4*>(x + xoff + k0 + q * 4);
        float4 bv[2];
#pragma unroll
        for (int q = 0; q < 2; ++q)
            bv[q] = *reinterpret_cast<const float4*>(
                w1e + (size_t)(k0 + bk) * HIDN + bn + bnq + q * 4);

        __syncthreads();
#pragma unroll
        for (int q = 0; q < 4; ++q) {
            As[q * 4 + 0][tid] = av[q].x;
            As[q * 4 + 1][tid] = av[q].y;
            As[q * 4 + 2][tid] = av[q].z;
            As[q * 4 + 3][tid] = av[q].w;
        }
#pragma unroll
        for (int q = 0; q < 2; ++q)
            *reinterpret_cast<float4*>(&Bs[bk][bnq + q * 4]) = bv[q];
        __syncthreads();

#pragma unroll
        for (int kk = 0; kk < BK; ++kk) {
            float4 a0 = *reinterpret_cast<const float4*>(&As[kk][ty * 8]);
            float4 a1 = *reinterpret_cast<const float4*>(&As[kk][ty * 8 + 4]);
            float4 b0 = *reinterpret_cast<const float4*>(&Bs[kk][tx * 8]);
            float4 b1v = *reinterpret_cast<const float4*>(&Bs[kk][tx * 8 + 4]);
            float a[8] = {a0.x, a0.y, a0.z, a0.w, a1.x, a1.y, a1.z, a1.w};
            float bb[8] = {b0.x, b0.y, b0.z, b0.w, b1v.x, b1v.y, b1v.z, b1v.w};
#pragma unroll
            for (int i = 0; i < 8; ++i)
#pragma unroll
                for (int j = 0; j < 8; ++j) acc[i][j] += a[i] * bb[j];
        }
    }

    int n0 = bn + tx * 8;
    int r0 = bm + ty * 8;
#pragma unroll
    for (int i = 0; i < 8; ++i) {
        int rr = r0 + i;
        if (rr < MROWS) {
            float* hp = h + (size_t)rr * HIDN + n0;
#pragma unroll
            for (int j = 0; j < 8; ++j) {
                float v = acc[i][j] + b1e[n0 + j];
                hp[j] = 0.5f * v * (1.0f + erff(v * 0.70710678118654752f));
            }
        }
    }
}

// ---------------- GEMM2: out += gate * (h @ w2[e] + b2[e]) scattered ---------
// M=2052, N=1024, K=4096
__global__ __launch_bounds__(128)
void gemm2_kernel(const float* __restrict__ h, const float* __restrict__ w2e,
                  const float* __restrict__ b2e, const int* __restrict__ sel,
                  const float* __restrict__ gate, float* __restrict__ out, int e) {
    int bm = blockIdx.x * BM;
    int bn = blockIdx.y * BN;
    int tid = threadIdx.x;
    int ty = tid >> 3, tx = tid & 7;

    __shared__ float As[BK][BM + 4];
    __shared__ float Bs[BK][BN];

    int r = bm + tid;
    size_t aoff = (r < MROWS) ? (size_t)r * HIDN : 0;

    float acc[8][8];
#pragma unroll
    for (int i = 0; i < 8; ++i)
#pragma unroll
        for (int j = 0; j < 8; ++j) acc[i][j] = 0.f;

    int bk  = tid >> 3;
    int bnq = (tid & 7) * 8;

    for (int k0 = 0; k0 < HIDN; k0 += BK) {
        float4 av[4];
#pragma unroll
        for (int q = 0; q < 4; ++q)
            av[q] = *reinterpret_cast<const float4*>(h + aoff + k0 + q * 4);
        float4 bv[2];
#pragma unroll
        for (int q = 0; q < 2; ++q)
            bv[q] = *reinterpret_cast<const float4*>(
                w2e + (size_t)(k0 + bk) * DIMD + bn + bnq + q * 4);

        __syncthreads();
#pragma unroll
        for (int q = 0; q < 4; ++q) {
            As[q * 4 + 0][tid] = av[q].x;
            As[q * 4 + 1][tid] = av[q].y;
            As[q * 4 + 2][tid] = av[q].z;
            As[q * 4 + 3][tid] = av[q].w;
        }
#pragma unroll
        for (int q = 0; q < 2; ++q)
            *reinterpret_cast<float4*>(&Bs[bk][bnq + q * 4]) = bv[q];
        __syncthreads();

#pragma unroll
        for (int kk = 0; kk < BK; ++kk) {
            float4 a0 = *reinterpret_cast<const float4*>(&As[kk][ty * 8]);
            float4 a1 = *reinterpret_cast<const float4*>(&As[kk][ty * 8 + 4]);
            float4 b0 = *reinterpret_cast<const float4*>(&Bs[kk][tx * 8]);
            float4 b1v = *reinterpret_cast<const float4*>(&Bs[kk][tx * 8 + 4]);
            float a[8] = {a0.x, a0.y, a0.z, a0.w, a1.x, a1.y, a1.z, a1.w};
            float bb[8] = {b0.x, b0.y, b0.z, b0.w, b1v.x, b1v.y, b1v.z, b1v.w};
#pragma unroll
            for (int i = 0; i < 8; ++i)
#pragma unroll
                for (int j = 0; j < 8; ++j) acc[i][j] += a[i] * bb[j];
        }
    }

    int n0 = bn + tx * 8;
    int r0 = bm + ty * 8;
#pragma unroll
    for (int i = 0; i < 8; ++i) {
        int rr = r0 + i;
        if (rr < MROWS) {
            int b = rr / CAPC, c = rr - b * CAPC;
            int tok = sel[(b * NEXP + e) * CAPC + c];
            float g  = gate[(b * NEXP + e) * CAPC + c];
            float* op = out + ((size_t)(b * SEQ + tok)) * DIMD + n0;
            // distinct tokens within an expert; expert kernels serialize on the
            // stream -> plain += is race-free (no atomics needed)
#pragma unroll
            for (int j = 0; j < 8; ++j) {
                float v = acc[i][j] + b2e[n0 + j];
                op[j] += g * v;
            }
        }
    }
}

extern "C" void kernel_launch(void* const* d_in, const int* in_sizes, int n_in,
                              void* d_out, int out_size, void* d_ws, size_t ws_size,
                              hipStream_t stream) {
    const float* x  = (const float*)d_in[0];
    const float* rw = (const float*)d_in[1];
    const float* w1 = (const float*)d_in[2];
    const float* b1 = (const float*)d_in[3];
    const float* w2 = (const float*)d_in[4];
    const float* b2 = (const float*)d_in[5];
    float* out = (float*)d_out;

    char* ws = (char*)d_ws;
    size_t off = 0;
    float* scores = (float*)(ws + off); off += (size_t)BATCH * NEXP * SEQ * 4;  off = (off + 255) & ~(size_t)255;
    int*   sel    = (int*)(ws + off);   off += (size_t)BATCH * NEXP * CAPC * 4; off = (off + 255) & ~(size_t)255;
    float* gate   = (float*)(ws + off); off += (size_t)BATCH * NEXP * CAPC * 4; off = (off + 255) & ~(size_t)255;
    float* h      = (float*)(ws + off); off += (size_t)MROWS * HIDN * 4;

    hipMemsetAsync(d_out, 0, (size_t)out_size * sizeof(float), stream);

    router_kernel<<<BATCH * SEQ, 64, 0, stream>>>(x, rw, scores);
    topk_kernel<<<BATCH * NEXP, 256, 0, stream>>>(scores, sel, gate);

    dim3 blk(128);
    dim3 g1((MROWS + BM - 1) / BM, HIDN / BN);
    dim3 g2((MROWS + BM - 1) / BM, DIMD / BN);
    for (int e = 0; e < NEXP; ++e) {
        gemm1_kernel<<<g1, blk, 0, stream>>>(x, w1 + (size_t)e * DIMD * HIDN,
                                             b1 + (size_t)e * HIDN, sel, h, e);
        gemm2_kernel<<<g2, blk, 0, stream>>>(h, w2 + (size_t)e * HIDN * DIMD,
                                             b2 + (size_t)e * DIMD, sel, gate, out, e);
    }
}

// Round 2
// 2375.977 us; speedup vs baseline: 3.4746x; 3.4746x over previous
//
#include <hip/hip_runtime.h>
#include <cstdint>

#define DIMD  1024
#define NEXP  8
#define HIDN  4096
#define BATCH 4
#define SEQ   2048
#define CAPC  513                  // int(2048*2.0/8)+1
#define RPEX  2176                 // rows per expert, padded to 17*128
#define TPEX  17                   // 128-row tiles per expert
#define MTOT  (NEXP * RPEX)        // 17408
#define MTILES (MTOT / 128)        // 136

typedef __bf16 bf16x8 __attribute__((ext_vector_type(8)));
typedef float  f32x4  __attribute__((ext_vector_type(4)));

__device__ __forceinline__ unsigned short f2bf(float f) {
    unsigned u = __float_as_uint(f);
    unsigned r = (u + 0x7FFFu + ((u >> 16) & 1u)) >> 16;
    return (unsigned short)r;
}
__device__ __forceinline__ void split1(float f, unsigned short& h, unsigned short& l) {
    h = f2bf(f);
    float hf = __uint_as_float(((unsigned)h) << 16);
    l = f2bf(f - hf);
}

// ---------------- router: scores_t [B][E][S] = softmax over E ----------------
__global__ __launch_bounds__(64)
void router_kernel(const float* __restrict__ x, const float* __restrict__ rw,
                   float* __restrict__ scores) {
    int token = blockIdx.x;
    int lane  = threadIdx.x;
    const float4* xr = reinterpret_cast<const float4*>(x + (size_t)token * DIMD);
    float4 xv[4];
#pragma unroll
    for (int j = 0; j < 4; ++j) xv[j] = xr[lane * 4 + j];
    float acc[NEXP];
#pragma unroll
    for (int e = 0; e < NEXP; ++e) {
        const float4* wr = reinterpret_cast<const float4*>(rw + (size_t)e * DIMD);
        float a = 0.f;
#pragma unroll
        for (int j = 0; j < 4; ++j) {
            float4 wv = wr[lane * 4 + j];
            a += xv[j].x * wv.x; a += xv[j].y * wv.y;
            a += xv[j].z * wv.z; a += xv[j].w * wv.w;
        }
#pragma unroll
        for (int off = 32; off > 0; off >>= 1) a += __shfl_xor(a, off);
        acc[e] = a;
    }
    float m = acc[0];
#pragma unroll
    for (int e = 1; e < NEXP; ++e) m = fmaxf(m, acc[e]);
    float s = 0.f;
#pragma unroll
    for (int e = 0; e < NEXP; ++e) { acc[e] = expf(acc[e] - m); s += acc[e]; }
    float inv = 1.f / s;
    if (lane == 0) {
        int b = token >> 11;
        int t = token & (SEQ - 1);
#pragma unroll
        for (int e = 0; e < NEXP; ++e)
            scores[((size_t)(b * NEXP + e)) * SEQ + t] = acc[e] * inv;
    }
}

// ---------------- expert-choice top-k via exact rank (stable, desc) ----------
__global__ __launch_bounds__(256)
void topk_kernel(const float* __restrict__ scores, int* __restrict__ sel,
                 float* __restrict__ gate) {
    int be = blockIdx.x;
    const float* sc = scores + (size_t)be * SEQ;
    __shared__ float s_sc[SEQ];
    for (int i = threadIdx.x; i < SEQ; i += 256) s_sc[i] = sc[i];
    __syncthreads();
    for (int i = threadIdx.x; i < SEQ; i += 256) {
        float v = s_sc[i];
        int rank = 0;
        for (int j = 0; j < SEQ; ++j) {
            float u = s_sc[j];
            rank += (u > v) || (u == v && j < i);
        }
        if (rank < CAPC) {
            sel [(size_t)be * CAPC + rank] = i;
            gate[(size_t)be * CAPC + rank] = v;
        }
    }
}

// ---------------- gather + split: A1 rows (padded) -> hi/lo bf16 -------------
__global__ __launch_bounds__(256)
void gather_kernel(const float* __restrict__ x, const int* __restrict__ sel,
                   unsigned short* __restrict__ dhi, unsigned short* __restrict__ dlo,
                   int row0) {
    int lr = blockIdx.x;
    int gr = row0 + lr;
    int e  = gr / RPEX;
    int rl = gr - e * RPEX;
    int t  = threadIdx.x;
    size_t dbase = (size_t)lr * DIMD + t * 4;
    if (rl < BATCH * CAPC) {
        int b = rl / CAPC, c = rl - b * CAPC;
        int tok = sel[(size_t)(b * NEXP + e) * CAPC + c];
        float4 v = *reinterpret_cast<const float4*>(x + ((size_t)(b * SEQ + tok)) * DIMD + t * 4);
        ushort4 h, l;
        split1(v.x, h.x, l.x); split1(v.y, h.y, l.y);
        split1(v.z, h.z, l.z); split1(v.w, h.w, l.w);
        *reinterpret_cast<ushort4*>(dhi + dbase) = h;
        *reinterpret_cast<ushort4*>(dlo + dbase) = l;
    } else {
        ushort4 z = {0, 0, 0, 0};
        *reinterpret_cast<ushort4*>(dhi + dbase) = z;
        *reinterpret_cast<ushort4*>(dlo + dbase) = z;
    }
}

// ------------- weight transpose + split: src[K][N] -> dst[N][K] hi/lo --------
__global__ __launch_bounds__(256)
void convT_kernel(const float* __restrict__ src, unsigned short* __restrict__ dhi,
                  unsigned short* __restrict__ dlo, int K, int N) {
    size_t eo = (size_t)blockIdx.z * K * N;
    src += eo; dhi += eo; dlo += eo;
    int k0 = blockIdx.x * 64, n0 = blockIdx.y * 64;
    __shared__ float T[64][65];
    int t = threadIdx.x;
    for (int i = t; i < 1024; i += 256) {
        int r = i >> 4, c4 = (i & 15) * 4;
        float4 v = *reinterpret_cast<const float4*>(src + (size_t)(k0 + r) * N + n0 + c4);
        T[r][c4 + 0] = v.x; T[r][c4 + 1] = v.y; T[r][c4 + 2] = v.z; T[r][c4 + 3] = v.w;
    }
    __syncthreads();
    for (int i = t; i < 1024; i += 256) {
        int n = i >> 4, kc = (i & 15) * 4;
        ushort4 h, l;
        split1(T[kc + 0][n], h.x, l.x); split1(T[kc + 1][n], h.y, l.y);
        split1(T[kc + 2][n], h.z, l.z); split1(T[kc + 3][n], h.w, l.w);
        size_t o = (size_t)(n0 + n) * K + k0 + kc;
        *reinterpret_cast<ushort4*>(dhi + o) = h;
        *reinterpret_cast<ushort4*>(dlo + o) = l;
    }
}

// ======================= split-bf16 3-pass MFMA GEMMs ========================
// Tile 128x128, BK=32, 256 thr (4 waves, 64x64 each, 4x4 frags 16x16x32).
// LDS rows padded to 40 ushorts (80 B = 5*16 B): b128 frag reads ~conflict-free.

#define GEMM_STAGE_DECLS \
    __shared__ __align__(16) unsigned short As_h[128][40]; \
    __shared__ __align__(16) unsigned short As_l[128][40]; \
    __shared__ __align__(16) unsigned short Bs_h[128][40]; \
    __shared__ __align__(16) unsigned short Bs_l[128][40];

__device__ __forceinline__ void mfma_triple(f32x4 acc[4][4], const bf16x8 ah[4],
                                            const bf16x8 al[4], const bf16x8 bh[4],
                                            const bf16x8 bl[4]) {
#pragma unroll
    for (int m = 0; m < 4; ++m)
#pragma unroll
        for (int n = 0; n < 4; ++n)
            acc[m][n] = __builtin_amdgcn_mfma_f32_16x16x32_bf16(ah[m], bh[n], acc[m][n], 0, 0, 0);
#pragma unroll
    for (int m = 0; m < 4; ++m)
#pragma unroll
        for (int n = 0; n < 4; ++n)
            acc[m][n] = __builtin_amdgcn_mfma_f32_16x16x32_bf16(ah[m], bl[n], acc[m][n], 0, 0, 0);
#pragma unroll
    for (int m = 0; m < 4; ++m)
#pragma unroll
        for (int n = 0; n < 4; ++n)
            acc[m][n] = __builtin_amdgcn_mfma_f32_16x16x32_bf16(al[m], bh[n], acc[m][n], 0, 0, 0);
}

// -------- GEMM1: h = gelu(A1 @ w1T^T + b1), K=1024, N=4096 -------------------
__global__ __launch_bounds__(256, 2)
void gemm1_mfma(const unsigned short* __restrict__ Ahi, const unsigned short* __restrict__ Alo,
                const unsigned short* __restrict__ Whi, const unsigned short* __restrict__ Wlo,
                const float* __restrict__ bias,
                unsigned short* __restrict__ Hhi, unsigned short* __restrict__ Hlo,
                int tile0, size_t wstride) {
    const int K = DIMD, N = HIDN;
    int bx = blockIdx.x, bn = blockIdx.y * 128;
    int e = (tile0 + bx) / TPEX;
    const unsigned short* Bh = Whi + (size_t)e * wstride;
    const unsigned short* Bl = Wlo + (size_t)e * wstride;
    const float* bs = bias + (size_t)e * N;
    int t = threadIdx.x;
    int l = t & 63, wid = t >> 6;
    int wr = wid >> 1, wc = wid & 1;
    int grp = l >> 4, li = l & 15;

    GEMM_STAGE_DECLS

    int srow = t >> 2, scg = t & 3, kc0 = scg * 8;
    size_t a0 = (size_t)(bx * 128 + srow) * K;
    size_t a1 = (size_t)(bx * 128 + srow + 64) * K;
    size_t b0 = (size_t)(bn + srow) * K;
    size_t b1o = (size_t)(bn + srow + 64) * K;

    f32x4 acc[4][4];
#pragma unroll
    for (int m = 0; m < 4; ++m)
#pragma unroll
        for (int n = 0; n < 4; ++n) { f32x4 z = {0.f, 0.f, 0.f, 0.f}; acc[m][n] = z; }

    uint4 rAh0, rAh1, rAl0, rAl1, rBh0, rBh1, rBl0, rBl1;
#define LOADK1(k0) do { \
    rAh0 = *(const uint4*)(Ahi + a0 + (k0) + kc0); rAh1 = *(const uint4*)(Ahi + a1 + (k0) + kc0); \
    rAl0 = *(const uint4*)(Alo + a0 + (k0) + kc0); rAl1 = *(const uint4*)(Alo + a1 + (k0) + kc0); \
    rBh0 = *(const uint4*)(Bh  + b0 + (k0) + kc0); rBh1 = *(const uint4*)(Bh  + b1o + (k0) + kc0); \
    rBl0 = *(const uint4*)(Bl  + b0 + (k0) + kc0); rBl1 = *(const uint4*)(Bl  + b1o + (k0) + kc0); } while (0)

    LOADK1(0);
    for (int kt = 0; kt < K; kt += 32) {
        __syncthreads();
        *(uint4*)&As_h[srow][kc0] = rAh0; *(uint4*)&As_h[srow + 64][kc0] = rAh1;
        *(uint4*)&As_l[srow][kc0] = rAl0; *(uint4*)&As_l[srow + 64][kc0] = rAl1;
        *(uint4*)&Bs_h[srow][kc0] = rBh0; *(uint4*)&Bs_h[srow + 64][kc0] = rBh1;
        *(uint4*)&Bs_l[srow][kc0] = rBl0; *(uint4*)&Bs_l[srow + 64][kc0] = rBl1;
        __syncthreads();
        if (kt + 32 < K) LOADK1(kt + 32);
        bf16x8 ah[4], al[4], bh[4], bl[4];
#pragma unroll
        for (int m = 0; m < 4; ++m) {
            ah[m] = *(const bf16x8*)&As_h[wr * 64 + m * 16 + li][grp * 8];
            al[m] = *(const bf16x8*)&As_l[wr * 64 + m * 16 + li][grp * 8];
        }
#pragma unroll
        for (int n = 0; n < 4; ++n) {
            bh[n] = *(const bf16x8*)&Bs_h[wc * 64 + n * 16 + li][grp * 8];
            bl[n] = *(const bf16x8*)&Bs_l[wc * 64 + n * 16 + li][grp * 8];
        }
        mfma_triple(acc, ah, al, bh, bl);
    }

    int hr0 = bx * 128 + wr * 64;
    int cb = bn + wc * 64;
#pragma unroll
    for (int m = 0; m < 4; ++m)
#pragma unroll
        for (int q = 0; q < 4; ++q) {
            int row = hr0 + m * 16 + grp * 4 + q;
#pragma unroll
            for (int n = 0; n < 4; ++n) {
                int col = cb + n * 16 + li;
                float v = acc[m][n][q] + bs[col];
                float g = 0.5f * v * (1.0f + erff(v * 0.70710678118654752f));
                unsigned short hh, hl;
                split1(g, hh, hl);
                Hhi[(size_t)row * HIDN + col] = hh;
                Hlo[(size_t)row * HIDN + col] = hl;
            }
        }
}

// -------- GEMM2: out += gate * (h @ w2T^T + b2) scatter, K=4096, N=1024 ------
__global__ __launch_bounds__(256, 2)
void gemm2_mfma(const unsigned short* __restrict__ Ahi, const unsigned short* __restrict__ Alo,
                const unsigned short* __restrict__ Whi, const unsigned short* __restrict__ Wlo,
                const float* __restrict__ bias, const int* __restrict__ sel,
                const float* __restrict__ gate, float* __restrict__ out,
                int tile0, size_t wstride) {
    const int K = HIDN, N = DIMD;
    int bx = blockIdx.x, bn = blockIdx.y * 128;
    int mt = tile0 + bx;
    int e = mt / TPEX;
    int rbase_e = (mt - e * TPEX) * 128;
    const unsigned short* Bh = Whi + (size_t)e * wstride;
    const unsigned short* Bl = Wlo + (size_t)e * wstride;
    const float* bs = bias + (size_t)e * N;
    int t = threadIdx.x;
    int l = t & 63, wid = t >> 6;
    int wr = wid >> 1, wc = wid & 1;
    int grp = l >> 4, li = l & 15;

    GEMM_STAGE_DECLS

    int srow = t >> 2, scg = t & 3, kc0 = scg * 8;
    size_t a0 = (size_t)(bx * 128 + srow) * K;
    size_t a1 = (size_t)(bx * 128 + srow + 64) * K;
    size_t b0 = (size_t)(bn + srow) * K;
    size_t b1o = (size_t)(bn + srow + 64) * K;

    f32x4 acc[4][4];
#pragma unroll
    for (int m = 0; m < 4; ++m)
#pragma unroll
        for (int n = 0; n < 4; ++n) { f32x4 z = {0.f, 0.f, 0.f, 0.f}; acc[m][n] = z; }

    uint4 rAh0, rAh1, rAl0, rAl1, rBh0, rBh1, rBl0, rBl1;
    LOADK1(0);
    for (int kt = 0; kt < K; kt += 32) {
        __syncthreads();
        *(uint4*)&As_h[srow][kc0] = rAh0; *(uint4*)&As_h[srow + 64][kc0] = rAh1;
        *(uint4*)&As_l[srow][kc0] = rAl0; *(uint4*)&As_l[srow + 64][kc0] = rAl1;
        *(uint4*)&Bs_h[srow][kc0] = rBh0; *(uint4*)&Bs_h[srow + 64][kc0] = rBh1;
        *(uint4*)&Bs_l[srow][kc0] = rBl0; *(uint4*)&Bs_l[srow + 64][kc0] = rBl1;
        __syncthreads();
        if (kt + 32 < K) LOADK1(kt + 32);
        bf16x8 ah[4], al[4], bh[4], bl[4];
#pragma unroll
        for (int m = 0; m < 4; ++m) {
            ah[m] = *(const bf16x8*)&As_h[wr * 64 + m * 16 + li][grp * 8];
            al[m] = *(const bf16x8*)&As_l[wr * 64 + m * 16 + li][grp * 8];
        }
#pragma unroll
        for (int n = 0; n < 4; ++n) {
            bh[n] = *(const bf16x8*)&Bs_h[wc * 64 + n * 16 + li][grp * 8];
            bl[n] = *(const bf16x8*)&Bs_l[wc * 64 + n * 16 + li][grp * 8];
        }
        mfma_triple(acc, ah, al, bh, bl);
    }

    int cb = bn + wc * 64;
#pragma unroll
    for (int m = 0; m < 4; ++m)
#pragma unroll
        for (int q = 0; q < 4; ++q) {
            int rloc = rbase_e + wr * 64 + m * 16 + grp * 4 + q;
            if (rloc < BATCH * CAPC) {
                int b = rloc / CAPC, c = rloc - b * CAPC;
                size_t idx = (size_t)(b * NEXP + e) * CAPC + c;
                int tok = sel[idx];
                float g = gate[idx];
                float* op = out + ((size_t)(b * SEQ + tok)) * DIMD;
#pragma unroll
                for (int n = 0; n < 4; ++n) {
                    int col = cb + n * 16 + li;
                    float v = acc[m][n][q] + bs[col];
                    atomicAdd(op + col, g * v);
                }
            }
        }
}

extern "C" void kernel_launch(void* const* d_in, const int* in_sizes, int n_in,
                              void* d_out, int out_size, void* d_ws, size_t ws_size,
                              hipStream_t stream) {
    (void)in_sizes; (void)n_in;
    const float* x  = (const float*)d_in[0];
    const float* rw = (const float*)d_in[1];
    const float* w1 = (const float*)d_in[2];
    const float* b1 = (const float*)d_in[3];
    const float* w2 = (const float*)d_in[4];
    const float* b2 = (const float*)d_in[5];
    float* out = (float*)d_out;

    char* ws = (char*)d_ws;
    size_t off = 0;
    auto alloc = [&](size_t bytes) -> char* {
        char* p = ws + off;
        off = (off + bytes + 255) & ~(size_t)255;
        return p;
    };

    float* scores = (float*)alloc((size_t)BATCH * NEXP * SEQ * 4);
    int*   sel    = (int*)  alloc((size_t)BATCH * NEXP * CAPC * 4);
    float* gate   = (float*)alloc((size_t)BATCH * NEXP * CAPC * 4);
    size_t common = off;

    const size_t A1F = (size_t)MTOT * DIMD * 2;        // fused A1 (one of hi/lo)
    const size_t WT1 = (size_t)NEXP * HIDN * DIMD * 2; // fused w1T
    const size_t WT2 = WT1;
    const size_t HF  = (size_t)MTOT * HIDN * 2;        // fused h
    size_t fused_need = common + 2 * A1F + 2 * WT1 + 2 * WT2 + 2 * HF + (1 << 20);

    hipMemsetAsync(d_out, 0, (size_t)out_size * sizeof(float), stream);
    router_kernel<<<BATCH * SEQ, 64, 0, stream>>>(x, rw, scores);
    topk_kernel<<<BATCH * NEXP, 256, 0, stream>>>(scores, sel, gate);

    if (ws_size >= fused_need) {
        unsigned short* A1h = (unsigned short*)alloc(A1F);
        unsigned short* A1l = (unsigned short*)alloc(A1F);
        unsigned short* W1h = (unsigned short*)alloc(WT1);
        unsigned short* W1l = (unsigned short*)alloc(WT1);
        unsigned short* W2h = (unsigned short*)alloc(WT2);
        unsigned short* W2l = (unsigned short*)alloc(WT2);
        unsigned short* Hh  = (unsigned short*)alloc(HF);
        unsigned short* Hl  = (unsigned short*)alloc(HF);

        gather_kernel<<<MTOT, 256, 0, stream>>>(x, sel, A1h, A1l, 0);
        convT_kernel<<<dim3(DIMD / 64, HIDN / 64, NEXP), 256, 0, stream>>>(w1, W1h, W1l, DIMD, HIDN);
        convT_kernel<<<dim3(HIDN / 64, DIMD / 64, NEXP), 256, 0, stream>>>(w2, W2h, W2l, HIDN, DIMD);
        gemm1_mfma<<<dim3(MTILES, HIDN / 128), 256, 0, stream>>>(
            A1h, A1l, W1h, W1l, b1, Hh, Hl, 0, (size_t)HIDN * DIMD);
        gemm2_mfma<<<dim3(MTILES, DIMD / 128), 256, 0, stream>>>(
            Hh, Hl, W2h, W2l, b2, sel, gate, out, 0, (size_t)HIDN * DIMD);
    } else {
        const size_t A1E = (size_t)RPEX * DIMD * 2;
        const size_t WE  = (size_t)HIDN * DIMD * 2;
        const size_t HE  = (size_t)RPEX * HIDN * 2;
        unsigned short* A1h = (unsigned short*)alloc(A1E);
        unsigned short* A1l = (unsigned short*)alloc(A1E);
        unsigned short* W1h = (unsigned short*)alloc(WE);
        unsigned short* W1l = (unsigned short*)alloc(WE);
        unsigned short* W2h = (unsigned short*)alloc(WE);
        unsigned short* W2l = (unsigned short*)alloc(WE);
        unsigned short* Hh  = (unsigned short*)alloc(HE);
        unsigned short* Hl  = (unsigned short*)alloc(HE);

        for (int e = 0; e < NEXP; ++e) {
            gather_kernel<<<RPEX, 256, 0, stream>>>(x, sel, A1h, A1l, e * RPEX);
            convT_kernel<<<dim3(DIMD / 64, HIDN / 64, 1), 256, 0, stream>>>(
                w1 + (size_t)e * DIMD * HIDN, W1h, W1l, DIMD, HIDN);
            gemm1_mfma<<<dim3(TPEX, HIDN / 128), 256, 0, stream>>>(
                A1h, A1l, W1h, W1l, b1, Hh, Hl, e * TPEX, 0);
            convT_kernel<<<dim3(HIDN / 64, DIMD / 64, 1), 256, 0, stream>>>(
                w2 + (size_t)e * HIDN * DIMD, W2h, W2l, HIDN, DIMD);
            gemm2_mfma<<<dim3(TPEX, DIMD / 128), 256, 0, stream>>>(
                Hh, Hl, W2h, W2l, b2, sel, gate, out, e * TPEX, 0);
        }
    }
}

// Round 3
// 2243.988 us; speedup vs baseline: 3.6790x; 1.0588x over previous
//
#include <hip/hip_runtime.h>
#include <cstdint>

#define DIMD  1024
#define NEXP  8
#define HIDN  4096
#define BATCH 4
#define SEQ   2048
#define CAPC  513                  // int(2048*2.0/8)+1
#define RPEX  2176                 // rows per expert, padded to 17*128
#define TPEX  17                   // 128-row tiles per expert
#define MTOT  (NEXP * RPEX)        // 17408
#define MTILES (MTOT / 128)        // 136

typedef __bf16 bf16x8 __attribute__((ext_vector_type(8)));
typedef float  f32x4  __attribute__((ext_vector_type(4)));

__device__ __forceinline__ unsigned short f2bf(float f) {
    unsigned u = __float_as_uint(f);
    unsigned r = (u + 0x7FFFu + ((u >> 16) & 1u)) >> 16;
    return (unsigned short)r;
}
__device__ __forceinline__ void split1(float f, unsigned short& h, unsigned short& l) {
    h = f2bf(f);
    float hf = __uint_as_float(((unsigned)h) << 16);
    l = f2bf(f - hf);
}

// ---------------- router: scores_t [B][E][S] = softmax over E ----------------
__global__ __launch_bounds__(64)
void router_kernel(const float* __restrict__ x, const float* __restrict__ rw,
                   float* __restrict__ scores) {
    int token = blockIdx.x;
    int lane  = threadIdx.x;
    const float4* xr = reinterpret_cast<const float4*>(x + (size_t)token * DIMD);
    float4 xv[4];
#pragma unroll
    for (int j = 0; j < 4; ++j) xv[j] = xr[lane * 4 + j];
    float acc[NEXP];
#pragma unroll
    for (int e = 0; e < NEXP; ++e) {
        const float4* wr = reinterpret_cast<const float4*>(rw + (size_t)e * DIMD);
        float a = 0.f;
#pragma unroll
        for (int j = 0; j < 4; ++j) {
            float4 wv = wr[lane * 4 + j];
            a += xv[j].x * wv.x; a += xv[j].y * wv.y;
            a += xv[j].z * wv.z; a += xv[j].w * wv.w;
        }
#pragma unroll
        for (int off = 32; off > 0; off >>= 1) a += __shfl_xor(a, off);
        acc[e] = a;
    }
    float m = acc[0];
#pragma unroll
    for (int e = 1; e < NEXP; ++e) m = fmaxf(m, acc[e]);
    float s = 0.f;
#pragma unroll
    for (int e = 0; e < NEXP; ++e) { acc[e] = expf(acc[e] - m); s += acc[e]; }
    float inv = 1.f / s;
    if (lane == 0) {
        int b = token >> 11;
        int t = token & (SEQ - 1);
#pragma unroll
        for (int e = 0; e < NEXP; ++e)
            scores[((size_t)(b * NEXP + e)) * SEQ + t] = acc[e] * inv;
    }
}

// ------- expert-choice top-k via exact rank (stable, desc), wave-parallel ----
// 1024 thr/block, 2 tokens/thread in regs; inner loop is an LDS broadcast.
__global__ __launch_bounds__(1024)
void topk_kernel(const float* __restrict__ scores, int* __restrict__ sel,
                 float* __restrict__ gate) {
    int be = blockIdx.x;
    const float* sc = scores + (size_t)be * SEQ;
    __shared__ float s_sc[SEQ];
    int t = threadIdx.x;
    s_sc[t] = sc[t];
    s_sc[t + 1024] = sc[t + 1024];
    __syncthreads();
    int i0 = t, i1 = t + 1024;
    float v0 = s_sc[i0], v1 = s_sc[i1];
    int r0 = 0, r1 = 0;
#pragma unroll 4
    for (int j = 0; j < SEQ; ++j) {
        float u = s_sc[j];
        r0 += (u > v0) || (u == v0 && j < i0);
        r1 += (u > v1) || (u == v1 && j < i1);
    }
    size_t base = (size_t)be * CAPC;
    if (r0 < CAPC) { sel[base + r0] = i0; gate[base + r0] = v0; }
    if (r1 < CAPC) { sel[base + r1] = i1; gate[base + r1] = v1; }
}

// ---------------- gather + split: A1 rows (padded) -> hi/lo bf16 -------------
__global__ __launch_bounds__(256)
void gather_kernel(const float* __restrict__ x, const int* __restrict__ sel,
                   unsigned short* __restrict__ dhi, unsigned short* __restrict__ dlo,
                   int row0) {
    int lr = blockIdx.x;
    int gr = row0 + lr;
    int e  = gr / RPEX;
    int rl = gr - e * RPEX;
    int t  = threadIdx.x;
    size_t dbase = (size_t)lr * DIMD + t * 4;
    if (rl < BATCH * CAPC) {
        int b = rl / CAPC, c = rl - b * CAPC;
        int tok = sel[(size_t)(b * NEXP + e) * CAPC + c];
        float4 v = *reinterpret_cast<const float4*>(x + ((size_t)(b * SEQ + tok)) * DIMD + t * 4);
        ushort4 h, l;
        split1(v.x, h.x, l.x); split1(v.y, h.y, l.y);
        split1(v.z, h.z, l.z); split1(v.w, h.w, l.w);
        *reinterpret_cast<ushort4*>(dhi + dbase) = h;
        *reinterpret_cast<ushort4*>(dlo + dbase) = l;
    } else {
        ushort4 z = {0, 0, 0, 0};
        *reinterpret_cast<ushort4*>(dhi + dbase) = z;
        *reinterpret_cast<ushort4*>(dlo + dbase) = z;
    }
}

// ------------- weight transpose + split: src[K][N] -> dst[N][K] hi/lo --------
__global__ __launch_bounds__(256)
void convT_kernel(const float* __restrict__ src, unsigned short* __restrict__ dhi,
                  unsigned short* __restrict__ dlo, int K, int N) {
    size_t eo = (size_t)blockIdx.z * K * N;
    src += eo; dhi += eo; dlo += eo;
    int k0 = blockIdx.x * 64, n0 = blockIdx.y * 64;
    __shared__ float T[64][65];
    int t = threadIdx.x;
    for (int i = t; i < 1024; i += 256) {
        int r = i >> 4, c4 = (i & 15) * 4;
        float4 v = *reinterpret_cast<const float4*>(src + (size_t)(k0 + r) * N + n0 + c4);
        T[r][c4 + 0] = v.x; T[r][c4 + 1] = v.y; T[r][c4 + 2] = v.z; T[r][c4 + 3] = v.w;
    }
    __syncthreads();
    for (int i = t; i < 1024; i += 256) {
        int n = i >> 4, kc = (i & 15) * 4;
        ushort4 h, l;
        split1(T[kc + 0][n], h.x, l.x); split1(T[kc + 1][n], h.y, l.y);
        split1(T[kc + 2][n], h.z, l.z); split1(T[kc + 3][n], h.w, l.w);
        size_t o = (size_t)(n0 + n) * K + k0 + kc;
        *reinterpret_cast<ushort4*>(dhi + o) = h;
        *reinterpret_cast<ushort4*>(dlo + o) = l;
    }
}

// ======================= split-bf16 3-pass MFMA GEMMs ========================
// Tile 128x128, BK=32, 256 thr (4 waves, 64x64 each, 4x4 frags 16x16x32).
// LDS rows padded to 40 ushorts (80 B = 5*16 B): b128 frag reads ~conflict-free.

#define GEMM_STAGE_DECLS \
    __shared__ __align__(16) unsigned short As_h[128][40]; \
    __shared__ __align__(16) unsigned short As_l[128][40]; \
    __shared__ __align__(16) unsigned short Bs_h[128][40]; \
    __shared__ __align__(16) unsigned short Bs_l[128][40];

__device__ __forceinline__ void mfma_triple(f32x4 acc[4][4], const bf16x8 ah[4],
                                            const bf16x8 al[4], const bf16x8 bh[4],
                                            const bf16x8 bl[4]) {
#pragma unroll
    for (int m = 0; m < 4; ++m)
#pragma unroll
        for (int n = 0; n < 4; ++n)
            acc[m][n] = __builtin_amdgcn_mfma_f32_16x16x32_bf16(ah[m], bh[n], acc[m][n], 0, 0, 0);
#pragma unroll
    for (int m = 0; m < 4; ++m)
#pragma unroll
        for (int n = 0; n < 4; ++n)
            acc[m][n] = __builtin_amdgcn_mfma_f32_16x16x32_bf16(ah[m], bl[n], acc[m][n], 0, 0, 0);
#pragma unroll
    for (int m = 0; m < 4; ++m)
#pragma unroll
        for (int n = 0; n < 4; ++n)
            acc[m][n] = __builtin_amdgcn_mfma_f32_16x16x32_bf16(al[m], bh[n], acc[m][n], 0, 0, 0);
}

// -------- GEMM1: h = gelu(A1 @ w1T^T + b1), K=1024, N=4096 -------------------
__global__ __launch_bounds__(256)
void gemm1_mfma(const unsigned short* __restrict__ Ahi, const unsigned short* __restrict__ Alo,
                const unsigned short* __restrict__ Whi, const unsigned short* __restrict__ Wlo,
                const float* __restrict__ bias,
                unsigned short* __restrict__ Hhi, unsigned short* __restrict__ Hlo,
                int tile0, size_t wstride) {
    const int K = DIMD, N = HIDN;
    int bx = blockIdx.x, bn = blockIdx.y * 128;
    int e = (tile0 + bx) / TPEX;
    const unsigned short* Bh = Whi + (size_t)e * wstride;
    const unsigned short* Bl = Wlo + (size_t)e * wstride;
    const float* bs = bias + (size_t)e * N;
    int t = threadIdx.x;
    int l = t & 63, wid = t >> 6;
    int wr = wid >> 1, wc = wid & 1;
    int grp = l >> 4, li = l & 15;

    GEMM_STAGE_DECLS

    int srow = t >> 2, scg = t & 3, kc0 = scg * 8;
    size_t a0 = (size_t)(bx * 128 + srow) * K;
    size_t a1 = (size_t)(bx * 128 + srow + 64) * K;
    size_t b0 = (size_t)(bn + srow) * K;
    size_t b1o = (size_t)(bn + srow + 64) * K;

    f32x4 acc[4][4];
#pragma unroll
    for (int m = 0; m < 4; ++m)
#pragma unroll
        for (int n = 0; n < 4; ++n) { f32x4 z = {0.f, 0.f, 0.f, 0.f}; acc[m][n] = z; }

    uint4 rAh0, rAh1, rAl0, rAl1, rBh0, rBh1, rBl0, rBl1;
#define LOADK1(k0) do { \
    rAh0 = *(const uint4*)(Ahi + a0 + (k0) + kc0); rAh1 = *(const uint4*)(Ahi + a1 + (k0) + kc0); \
    rAl0 = *(const uint4*)(Alo + a0 + (k0) + kc0); rAl1 = *(const uint4*)(Alo + a1 + (k0) + kc0); \
    rBh0 = *(const uint4*)(Bh  + b0 + (k0) + kc0); rBh1 = *(const uint4*)(Bh  + b1o + (k0) + kc0); \
    rBl0 = *(const uint4*)(Bl  + b0 + (k0) + kc0); rBl1 = *(const uint4*)(Bl  + b1o + (k0) + kc0); } while (0)

    LOADK1(0);
    for (int kt = 0; kt < K; kt += 32) {
        __syncthreads();
        *(uint4*)&As_h[srow][kc0] = rAh0; *(uint4*)&As_h[srow + 64][kc0] = rAh1;
        *(uint4*)&As_l[srow][kc0] = rAl0; *(uint4*)&As_l[srow + 64][kc0] = rAl1;
        *(uint4*)&Bs_h[srow][kc0] = rBh0; *(uint4*)&Bs_h[srow + 64][kc0] = rBh1;
        *(uint4*)&Bs_l[srow][kc0] = rBl0; *(uint4*)&Bs_l[srow + 64][kc0] = rBl1;
        __syncthreads();
        if (kt + 32 < K) LOADK1(kt + 32);
        bf16x8 ah[4], al[4], bh[4], bl[4];
#pragma unroll
        for (int m = 0; m < 4; ++m) {
            ah[m] = *(const bf16x8*)&As_h[wr * 64 + m * 16 + li][grp * 8];
            al[m] = *(const bf16x8*)&As_l[wr * 64 + m * 16 + li][grp * 8];
        }
#pragma unroll
        for (int n = 0; n < 4; ++n) {
            bh[n] = *(const bf16x8*)&Bs_h[wc * 64 + n * 16 + li][grp * 8];
            bl[n] = *(const bf16x8*)&Bs_l[wc * 64 + n * 16 + li][grp * 8];
        }
        mfma_triple(acc, ah, al, bh, bl);
    }

    int hr0 = bx * 128 + wr * 64;
    int cb = bn + wc * 64;
#pragma unroll
    for (int m = 0; m < 4; ++m)
#pragma unroll
        for (int q = 0; q < 4; ++q) {
            int row = hr0 + m * 16 + grp * 4 + q;
#pragma unroll
            for (int n = 0; n < 4; ++n) {
                int col = cb + n * 16 + li;
                float v = acc[m][n][q] + bs[col];
                float g = 0.5f * v * (1.0f + erff(v * 0.70710678118654752f));
                unsigned short hh, hl;
                split1(g, hh, hl);
                Hhi[(size_t)row * HIDN + col] = hh;
                Hlo[(size_t)row * HIDN + col] = hl;
            }
        }
}

// -------- GEMM2: out += gate * (h @ w2T^T + b2) scatter, K=4096, N=1024 ------
__global__ __launch_bounds__(256)
void gemm2_mfma(const unsigned short* __restrict__ Ahi, const unsigned short* __restrict__ Alo,
                const unsigned short* __restrict__ Whi, const unsigned short* __restrict__ Wlo,
                const float* __restrict__ bias, const int* __restrict__ sel,
                const float* __restrict__ gate, float* __restrict__ out,
                int tile0, size_t wstride) {
    const int K = HIDN, N = DIMD;
    int bx = blockIdx.x, bn = blockIdx.y * 128;
    int mt = tile0 + bx;
    int e = mt / TPEX;
    int rbase_e = (mt - e * TPEX) * 128;
    const unsigned short* Bh = Whi + (size_t)e * wstride;
    const unsigned short* Bl = Wlo + (size_t)e * wstride;
    const float* bs = bias + (size_t)e * N;
    int t = threadIdx.x;
    int l = t & 63, wid = t >> 6;
    int wr = wid >> 1, wc = wid & 1;
    int grp = l >> 4, li = l & 15;

    GEMM_STAGE_DECLS

    int srow = t >> 2, scg = t & 3, kc0 = scg * 8;
    size_t a0 = (size_t)(bx * 128 + srow) * K;
    size_t a1 = (size_t)(bx * 128 + srow + 64) * K;
    size_t b0 = (size_t)(bn + srow) * K;
    size_t b1o = (size_t)(bn + srow + 64) * K;

    f32x4 acc[4][4];
#pragma unroll
    for (int m = 0; m < 4; ++m)
#pragma unroll
        for (int n = 0; n < 4; ++n) { f32x4 z = {0.f, 0.f, 0.f, 0.f}; acc[m][n] = z; }

    uint4 rAh0, rAh1, rAl0, rAl1, rBh0, rBh1, rBl0, rBl1;
    LOADK1(0);
    for (int kt = 0; kt < K; kt += 32) {
        __syncthreads();
        *(uint4*)&As_h[srow][kc0] = rAh0; *(uint4*)&As_h[srow + 64][kc0] = rAh1;
        *(uint4*)&As_l[srow][kc0] = rAl0; *(uint4*)&As_l[srow + 64][kc0] = rAl1;
        *(uint4*)&Bs_h[srow][kc0] = rBh0; *(uint4*)&Bs_h[srow + 64][kc0] = rBh1;
        *(uint4*)&Bs_l[srow][kc0] = rBl0; *(uint4*)&Bs_l[srow + 64][kc0] = rBl1;
        __syncthreads();
        if (kt + 32 < K) LOADK1(kt + 32);
        bf16x8 ah[4], al[4], bh[4], bl[4];
#pragma unroll
        for (int m = 0; m < 4; ++m) {
            ah[m] = *(const bf16x8*)&As_h[wr * 64 + m * 16 + li][grp * 8];
            al[m] = *(const bf16x8*)&As_l[wr * 64 + m * 16 + li][grp * 8];
        }
#pragma unroll
        for (int n = 0; n < 4; ++n) {
            bh[n] = *(const bf16x8*)&Bs_h[wc * 64 + n * 16 + li][grp * 8];
            bl[n] = *(const bf16x8*)&Bs_l[wc * 64 + n * 16 + li][grp * 8];
        }
        mfma_triple(acc, ah, al, bh, bl);
    }

    int cb = bn + wc * 64;
#pragma unroll
    for (int m = 0; m < 4; ++m)
#pragma unroll
        for (int q = 0; q < 4; ++q) {
            int rloc = rbase_e + wr * 64 + m * 16 + grp * 4 + q;
            if (rloc < BATCH * CAPC) {
                int b = rloc / CAPC, c = rloc - b * CAPC;
                size_t idx = (size_t)(b * NEXP + e) * CAPC + c;
                int tok = sel[idx];
                float g = gate[idx];
                float* op = out + ((size_t)(b * SEQ + tok)) * DIMD;
#pragma unroll
                for (int n = 0; n < 4; ++n) {
                    int col = cb + n * 16 + li;
                    float v = acc[m][n][q] + bs[col];
                    atomicAdd(op + col, g * v);
                }
            }
        }
}

extern "C" void kernel_launch(void* const* d_in, const int* in_sizes, int n_in,
                              void* d_out, int out_size, void* d_ws, size_t ws_size,
                              hipStream_t stream) {
    (void)in_sizes; (void)n_in;
    const float* x  = (const float*)d_in[0];
    const float* rw = (const float*)d_in[1];
    const float* w1 = (const float*)d_in[2];
    const float* b1 = (const float*)d_in[3];
    const float* w2 = (const float*)d_in[4];
    const float* b2 = (const float*)d_in[5];
    float* out = (float*)d_out;

    char* ws = (char*)d_ws;
    size_t off = 0;
    auto alloc = [&](size_t bytes) -> char* {
        char* p = ws + off;
        off = (off + bytes + 255) & ~(size_t)255;
        return p;
    };

    float* scores = (float*)alloc((size_t)BATCH * NEXP * SEQ * 4);
    int*   sel    = (int*)  alloc((size_t)BATCH * NEXP * CAPC * 4);
    float* gate   = (float*)alloc((size_t)BATCH * NEXP * CAPC * 4);
    size_t common = off;

    const size_t A1F = (size_t)MTOT * DIMD * 2;        // fused A1 (one of hi/lo)
    const size_t WT1 = (size_t)NEXP * HIDN * DIMD * 2; // fused w1T
    const size_t WT2 = WT1;
    const size_t HF  = (size_t)MTOT * HIDN * 2;        // fused h
    size_t fused_need = common + 2 * A1F + 2 * WT1 + 2 * WT2 + 2 * HF + (1 << 20);

    hipMemsetAsync(d_out, 0, (size_t)out_size * sizeof(float), stream);
    router_kernel<<<BATCH * SEQ, 64, 0, stream>>>(x, rw, scores);
    topk_kernel<<<BATCH * NEXP, 1024, 0, stream>>>(scores, sel, gate);

    if (ws_size >= fused_need) {
        unsigned short* A1h = (unsigned short*)alloc(A1F);
        unsigned short* A1l = (unsigned short*)alloc(A1F);
        unsigned short* W1h = (unsigned short*)alloc(WT1);
        unsigned short* W1l = (unsigned short*)alloc(WT1);
        unsigned short* W2h = (unsigned short*)alloc(WT2);
        unsigned short* W2l = (unsigned short*)alloc(WT2);
        unsigned short* Hh  = (unsigned short*)alloc(HF);
        unsigned short* Hl  = (unsigned short*)alloc(HF);

        gather_kernel<<<MTOT, 256, 0, stream>>>(x, sel, A1h, A1l, 0);
        convT_kernel<<<dim3(DIMD / 64, HIDN / 64, NEXP), 256, 0, stream>>>(w1, W1h, W1l, DIMD, HIDN);
        convT_kernel<<<dim3(HIDN / 64, DIMD / 64, NEXP), 256, 0, stream>>>(w2, W2h, W2l, HIDN, DIMD);
        gemm1_mfma<<<dim3(MTILES, HIDN / 128), 256, 0, stream>>>(
            A1h, A1l, W1h, W1l, b1, Hh, Hl, 0, (size_t)HIDN * DIMD);
        gemm2_mfma<<<dim3(MTILES, DIMD / 128), 256, 0, stream>>>(
            Hh, Hl, W2h, W2l, b2, sel, gate, out, 0, (size_t)HIDN * DIMD);
    } else {
        const size_t A1E = (size_t)RPEX * DIMD * 2;
        const size_t WE  = (size_t)HIDN * DIMD * 2;
        const size_t HE  = (size_t)RPEX * HIDN * 2;
        unsigned short* A1h = (unsigned short*)alloc(A1E);
        unsigned short* A1l = (unsigned short*)alloc(A1E);
        unsigned short* W1h = (unsigned short*)alloc(WE);
        unsigned short* W1l = (unsigned short*)alloc(WE);
        unsigned short* W2h = (unsigned short*)alloc(WE);
        unsigned short* W2l = (unsigned short*)alloc(WE);
        unsigned short* Hh  = (unsigned short*)alloc(HE);
        unsigned short* Hl  = (unsigned short*)alloc(HE);

        for (int e = 0; e < NEXP; ++e) {
            gather_kernel<<<RPEX, 256, 0, stream>>>(x, sel, A1h, A1l, e * RPEX);
            convT_kernel<<<dim3(DIMD / 64, HIDN / 64, 1), 256, 0, stream>>>(
                w1 + (size_t)e * DIMD * HIDN, W1h, W1l, DIMD, HIDN);
            gemm1_mfma<<<dim3(TPEX, HIDN / 128), 256, 0, stream>>>(
                A1h, A1l, W1h, W1l, b1, Hh, Hl, e * TPEX, 0);
            convT_kernel<<<dim3(HIDN / 64, DIMD / 64, 1), 256, 0, stream>>>(
                w2 + (size_t)e * HIDN * DIMD, W2h, W2l, HIDN, DIMD);
            gemm2_mfma<<<dim3(TPEX, DIMD / 128), 256, 0, stream>>>(
                Hh, Hl, W2h, W2l, b2, sel, gate, out, e * TPEX, 0);
        }
    }
}

// Round 4
// 1488.708 us; speedup vs baseline: 5.5455x; 1.5073x over previous
//
#include <hip/hip_runtime.h>
#include <cstdint>

#define DIMD  1024
#define NEXP  8
#define HIDN  4096
#define BATCH 4
#define SEQ   2048
#define CAPC  513                  // int(2048*2.0/8)+1
#define RPEX  2176                 // rows per expert, padded to 17*128
#define TPEX  17                   // 128-row tiles per expert
#define MTOT  (NEXP * RPEX)        // 17408
#define MTILES (MTOT / 128)        // 136

typedef __bf16 bf16x8 __attribute__((ext_vector_type(8)));
typedef float  f32x4  __attribute__((ext_vector_type(4)));

__device__ __forceinline__ unsigned short f2bf(float f) {
    unsigned u = __float_as_uint(f);
    unsigned r = (u + 0x7FFFu + ((u >> 16) & 1u)) >> 16;
    return (unsigned short)r;
}
__device__ __forceinline__ void split1(float f, unsigned short& h, unsigned short& l) {
    h = f2bf(f);
    float hf = __uint_as_float(((unsigned)h) << 16);
    l = f2bf(f - hf);
}

// ---------------- router: scores_t [B][E][S] = softmax over E ----------------
__global__ __launch_bounds__(64)
void router_kernel(const float* __restrict__ x, const float* __restrict__ rw,
                   float* __restrict__ scores) {
    int token = blockIdx.x;
    int lane  = threadIdx.x;
    const float4* xr = reinterpret_cast<const float4*>(x + (size_t)token * DIMD);
    float4 xv[4];
#pragma unroll
    for (int j = 0; j < 4; ++j) xv[j] = xr[lane * 4 + j];
    float acc[NEXP];
#pragma unroll
    for (int e = 0; e < NEXP; ++e) {
        const float4* wr = reinterpret_cast<const float4*>(rw + (size_t)e * DIMD);
        float a = 0.f;
#pragma unroll
        for (int j = 0; j < 4; ++j) {
            float4 wv = wr[lane * 4 + j];
            a += xv[j].x * wv.x; a += xv[j].y * wv.y;
            a += xv[j].z * wv.z; a += xv[j].w * wv.w;
        }
#pragma unroll
        for (int off = 32; off > 0; off >>= 1) a += __shfl_xor(a, off);
        acc[e] = a;
    }
    float m = acc[0];
#pragma unroll
    for (int e = 1; e < NEXP; ++e) m = fmaxf(m, acc[e]);
    float s = 0.f;
#pragma unroll
    for (int e = 0; e < NEXP; ++e) { acc[e] = expf(acc[e] - m); s += acc[e]; }
    float inv = 1.f / s;
    if (lane == 0) {
        int b = token >> 11;
        int t = token & (SEQ - 1);
#pragma unroll
        for (int e = 0; e < NEXP; ++e)
            scores[((size_t)(b * NEXP + e)) * SEQ + t] = acc[e] * inv;
    }
}

// ------- expert-choice top-k via exact rank (stable, desc), 256 blocks -------
// block = one (b,e) pair x one 256-token i-chunk; j-loop is LDS broadcast.
__global__ __launch_bounds__(256)
void topk_kernel(const float* __restrict__ scores, int* __restrict__ sel,
                 float* __restrict__ gate) {
    int be    = blockIdx.x >> 3;
    int chunk = blockIdx.x & 7;
    const float* sc = scores + (size_t)be * SEQ;
    __shared__ float s_sc[SEQ];
    int t = threadIdx.x;
#pragma unroll
    for (int q = 0; q < 8; ++q) s_sc[t + q * 256] = sc[t + q * 256];
    __syncthreads();
    int i = chunk * 256 + t;
    float v = s_sc[i];
    int r = 0;
#pragma unroll 8
    for (int j = 0; j < SEQ; ++j) {
        float u = s_sc[j];
        r += (u > v) || (u == v && j < i);
    }
    if (r < CAPC) {
        sel [(size_t)be * CAPC + r] = i;
        gate[(size_t)be * CAPC + r] = v;
    }
}

// ---------------- gather + split: A1 rows (padded) -> hi/lo bf16 -------------
__global__ __launch_bounds__(256)
void gather_kernel(const float* __restrict__ x, const int* __restrict__ sel,
                   unsigned short* __restrict__ dhi, unsigned short* __restrict__ dlo,
                   int row0) {
    int lr = blockIdx.x;
    int gr = row0 + lr;
    int e  = gr / RPEX;
    int rl = gr - e * RPEX;
    int t  = threadIdx.x;
    size_t dbase = (size_t)lr * DIMD + t * 4;
    if (rl < BATCH * CAPC) {
        int b = rl / CAPC, c = rl - b * CAPC;
        int tok = sel[(size_t)(b * NEXP + e) * CAPC + c];
        float4 v = *reinterpret_cast<const float4*>(x + ((size_t)(b * SEQ + tok)) * DIMD + t * 4);
        ushort4 h, l;
        split1(v.x, h.x, l.x); split1(v.y, h.y, l.y);
        split1(v.z, h.z, l.z); split1(v.w, h.w, l.w);
        *reinterpret_cast<ushort4*>(dhi + dbase) = h;
        *reinterpret_cast<ushort4*>(dlo + dbase) = l;
    } else {
        ushort4 z = {0, 0, 0, 0};
        *reinterpret_cast<ushort4*>(dhi + dbase) = z;
        *reinterpret_cast<ushort4*>(dlo + dbase) = z;
    }
}

// ------ weight transpose+split of a sub-block: src[k0+kLen][n0+nLen] ---------
// src is [Ksrc x Nsrc] row-major (expert stride srcEStride);
// dst is [nLen x kLen] row-major (expert stride nLen*kLen), hi/lo bf16.
__global__ __launch_bounds__(256)
void convT_kernel(const float* __restrict__ src, unsigned short* __restrict__ dhi,
                  unsigned short* __restrict__ dlo, int Nsrc, size_t srcEStride,
                  int k0, int n0, int kLen, int nLen) {
    int e = blockIdx.z;
    src += (size_t)e * srcEStride;
    size_t dstE = (size_t)e * kLen * nLen;
    dhi += dstE; dlo += dstE;
    int kb = blockIdx.x * 64, nb = blockIdx.y * 64;
    __shared__ float T[64][65];
    int t = threadIdx.x;
    for (int i = t; i < 1024; i += 256) {
        int r = i >> 4, c4 = (i & 15) * 4;
        float4 v = *reinterpret_cast<const float4*>(
            src + (size_t)(k0 + kb + r) * Nsrc + n0 + nb + c4);
        T[r][c4 + 0] = v.x; T[r][c4 + 1] = v.y; T[r][c4 + 2] = v.z; T[r][c4 + 3] = v.w;
    }
    __syncthreads();
    for (int i = t; i < 1024; i += 256) {
        int n = i >> 4, kc = (i & 15) * 4;
        ushort4 h, l;
        split1(T[kc + 0][n], h.x, l.x); split1(T[kc + 1][n], h.y, l.y);
        split1(T[kc + 2][n], h.z, l.z); split1(T[kc + 3][n], h.w, l.w);
        size_t o = (size_t)(nb + n) * kLen + kb + kc;
        *reinterpret_cast<ushort4*>(dhi + o) = h;
        *reinterpret_cast<ushort4*>(dlo + o) = l;
    }
}

// ======================= split-bf16 3-pass MFMA GEMMs ========================
// Tile 128x128, BK=32, 256 thr (4 waves, 64x64 each, 4x4 frags 16x16x32).
// LDS rows padded to 40 ushorts (80 B = 5*16 B): b128 frag reads ~conflict-free.

#define GEMM_STAGE_DECLS \
    __shared__ __align__(16) unsigned short As_h[128][40]; \
    __shared__ __align__(16) unsigned short As_l[128][40]; \
    __shared__ __align__(16) unsigned short Bs_h[128][40]; \
    __shared__ __align__(16) unsigned short Bs_l[128][40];

__device__ __forceinline__ void mfma_triple(f32x4 acc[4][4], const bf16x8 ah[4],
                                            const bf16x8 al[4], const bf16x8 bh[4],
                                            const bf16x8 bl[4]) {
#pragma unroll
    for (int m = 0; m < 4; ++m)
#pragma unroll
        for (int n = 0; n < 4; ++n)
            acc[m][n] = __builtin_amdgcn_mfma_f32_16x16x32_bf16(ah[m], bh[n], acc[m][n], 0, 0, 0);
#pragma unroll
    for (int m = 0; m < 4; ++m)
#pragma unroll
        for (int n = 0; n < 4; ++n)
            acc[m][n] = __builtin_amdgcn_mfma_f32_16x16x32_bf16(ah[m], bl[n], acc[m][n], 0, 0, 0);
#pragma unroll
    for (int m = 0; m < 4; ++m)
#pragma unroll
        for (int n = 0; n < 4; ++n)
            acc[m][n] = __builtin_amdgcn_mfma_f32_16x16x32_bf16(al[m], bh[n], acc[m][n], 0, 0, 0);
}

#define LOADK1(k0c) do { \
    rAh0 = *(const uint4*)(Ahi + a0 + (k0c) + kc0); rAh1 = *(const uint4*)(Ahi + a1 + (k0c) + kc0); \
    rAl0 = *(const uint4*)(Alo + a0 + (k0c) + kc0); rAl1 = *(const uint4*)(Alo + a1 + (k0c) + kc0); \
    rBh0 = *(const uint4*)(Bh  + b0 + (k0c) + kc0); rBh1 = *(const uint4*)(Bh  + b1o + (k0c) + kc0); \
    rBl0 = *(const uint4*)(Bl  + b0 + (k0c) + kc0); rBl1 = *(const uint4*)(Bl  + b1o + (k0c) + kc0); } while (0)

// -------- GEMM1: H[:,chunk] = gelu(A1 @ W1c^T + b1[nbias0+...]), K=1024 ------
__global__ __launch_bounds__(256)
void gemm1_mfma(const unsigned short* __restrict__ Ahi, const unsigned short* __restrict__ Alo,
                const unsigned short* __restrict__ Whi, const unsigned short* __restrict__ Wlo,
                const float* __restrict__ bias,
                unsigned short* __restrict__ Hhi, unsigned short* __restrict__ Hlo,
                int tile0, size_t wstride, int nbias0, int ldh) {
    const int K = DIMD;
    int bx = blockIdx.x, bn = blockIdx.y * 128;
    int e = (tile0 + bx) / TPEX;
    const unsigned short* Bh = Whi + (size_t)e * wstride;
    const unsigned short* Bl = Wlo + (size_t)e * wstride;
    int t = threadIdx.x;
    int l = t & 63, wid = t >> 6;
    int wr = wid >> 1, wc = wid & 1;
    int grp = l >> 4, li = l & 15;

    GEMM_STAGE_DECLS

    int srow = t >> 2, scg = t & 3, kc0 = scg * 8;
    size_t a0 = (size_t)(bx * 128 + srow) * K;
    size_t a1 = (size_t)(bx * 128 + srow + 64) * K;
    size_t b0 = (size_t)(bn + srow) * K;
    size_t b1o = (size_t)(bn + srow + 64) * K;

    f32x4 acc[4][4];
#pragma unroll
    for (int m = 0; m < 4; ++m)
#pragma unroll
        for (int n = 0; n < 4; ++n) { f32x4 z = {0.f, 0.f, 0.f, 0.f}; acc[m][n] = z; }

    uint4 rAh0, rAh1, rAl0, rAl1, rBh0, rBh1, rBl0, rBl1;
    LOADK1(0);
    for (int kt = 0; kt < K; kt += 32) {
        __syncthreads();
        *(uint4*)&As_h[srow][kc0] = rAh0; *(uint4*)&As_h[srow + 64][kc0] = rAh1;
        *(uint4*)&As_l[srow][kc0] = rAl0; *(uint4*)&As_l[srow + 64][kc0] = rAl1;
        *(uint4*)&Bs_h[srow][kc0] = rBh0; *(uint4*)&Bs_h[srow + 64][kc0] = rBh1;
        *(uint4*)&Bs_l[srow][kc0] = rBl0; *(uint4*)&Bs_l[srow + 64][kc0] = rBl1;
        __syncthreads();
        if (kt + 32 < K) LOADK1(kt + 32);
        bf16x8 ah[4], al[4], bh[4], bl[4];
#pragma unroll
        for (int m = 0; m < 4; ++m) {
            ah[m] = *(const bf16x8*)&As_h[wr * 64 + m * 16 + li][grp * 8];
            al[m] = *(const bf16x8*)&As_l[wr * 64 + m * 16 + li][grp * 8];
        }
#pragma unroll
        for (int n = 0; n < 4; ++n) {
            bh[n] = *(const bf16x8*)&Bs_h[wc * 64 + n * 16 + li][grp * 8];
            bl[n] = *(const bf16x8*)&Bs_l[wc * 64 + n * 16 + li][grp * 8];
        }
        mfma_triple(acc, ah, al, bh, bl);
    }

    int hr0 = bx * 128 + wr * 64;
    int cb = bn + wc * 64;
#pragma unroll
    for (int m = 0; m < 4; ++m)
#pragma unroll
        for (int q = 0; q < 4; ++q) {
            int row = hr0 + m * 16 + grp * 4 + q;
#pragma unroll
            for (int n = 0; n < 4; ++n) {
                int col = cb + n * 16 + li;
                float v = acc[m][n][q] + bias[(size_t)e * HIDN + nbias0 + col];
                float g = 0.5f * v * (1.0f + erff(v * 0.70710678118654752f));
                unsigned short hh, hl;
                split1(g, hh, hl);
                Hhi[(size_t)row * ldh + col] = hh;
                Hlo[(size_t)row * ldh + col] = hl;
            }
        }
}

// -------- GEMM2: out += gate * (Hc @ W2c^T [+ b2]) scatter, K runtime --------
__global__ __launch_bounds__(256)
void gemm2_mfma(const unsigned short* __restrict__ Ahi, const unsigned short* __restrict__ Alo,
                const unsigned short* __restrict__ Whi, const unsigned short* __restrict__ Wlo,
                const float* __restrict__ bias, const int* __restrict__ sel,
                const float* __restrict__ gate, float* __restrict__ out,
                int tile0, size_t wstride, int K) {
    int bx = blockIdx.x, bn = blockIdx.y * 128;
    int mt = tile0 + bx;
    int e = mt / TPEX;
    int rbase_e = (mt - e * TPEX) * 128;
    const unsigned short* Bh = Whi + (size_t)e * wstride;
    const unsigned short* Bl = Wlo + (size_t)e * wstride;
    int t = threadIdx.x;
    int l = t & 63, wid = t >> 6;
    int wr = wid >> 1, wc = wid & 1;
    int grp = l >> 4, li = l & 15;

    GEMM_STAGE_DECLS

    int srow = t >> 2, scg = t & 3, kc0 = scg * 8;
    size_t a0 = (size_t)(bx * 128 + srow) * K;
    size_t a1 = (size_t)(bx * 128 + srow + 64) * K;
    size_t b0 = (size_t)(bn + srow) * K;
    size_t b1o = (size_t)(bn + srow + 64) * K;

    f32x4 acc[4][4];
#pragma unroll
    for (int m = 0; m < 4; ++m)
#pragma unroll
        for (int n = 0; n < 4; ++n) { f32x4 z = {0.f, 0.f, 0.f, 0.f}; acc[m][n] = z; }

    uint4 rAh0, rAh1, rAl0, rAl1, rBh0, rBh1, rBl0, rBl1;
    LOADK1(0);
    for (int kt = 0; kt < K; kt += 32) {
        __syncthreads();
        *(uint4*)&As_h[srow][kc0] = rAh0; *(uint4*)&As_h[srow + 64][kc0] = rAh1;
        *(uint4*)&As_l[srow][kc0] = rAl0; *(uint4*)&As_l[srow + 64][kc0] = rAl1;
        *(uint4*)&Bs_h[srow][kc0] = rBh0; *(uint4*)&Bs_h[srow + 64][kc0] = rBh1;
        *(uint4*)&Bs_l[srow][kc0] = rBl0; *(uint4*)&Bs_l[srow + 64][kc0] = rBl1;
        __syncthreads();
        if (kt + 32 < K) LOADK1(kt + 32);
        bf16x8 ah[4], al[4], bh[4], bl[4];
#pragma unroll
        for (int m = 0; m < 4; ++m) {
            ah[m] = *(const bf16x8*)&As_h[wr * 64 + m * 16 + li][grp * 8];
            al[m] = *(const bf16x8*)&As_l[wr * 64 + m * 16 + li][grp * 8];
        }
#pragma unroll
        for (int n = 0; n < 4; ++n) {
            bh[n] = *(const bf16x8*)&Bs_h[wc * 64 + n * 16 + li][grp * 8];
            bl[n] = *(const bf16x8*)&Bs_l[wc * 64 + n * 16 + li][grp * 8];
        }
        mfma_triple(acc, ah, al, bh, bl);
    }

    int cb = bn + wc * 64;
#pragma unroll
    for (int m = 0; m < 4; ++m)
#pragma unroll
        for (int q = 0; q < 4; ++q) {
            int rloc = rbase_e + wr * 64 + m * 16 + grp * 4 + q;
            if (rloc < BATCH * CAPC) {
                int b = rloc / CAPC, c = rloc - b * CAPC;
                size_t idx = (size_t)(b * NEXP + e) * CAPC + c;
                int tok = sel[idx];
                float g = gate[idx];
                float* op = out + ((size_t)(b * SEQ + tok)) * DIMD;
#pragma unroll
                for (int n = 0; n < 4; ++n) {
                    int col = cb + n * 16 + li;
                    float v = acc[m][n][q];
                    if (bias) v += bias[(size_t)e * DIMD + col];
                    atomicAdd(op + col, g * v);
                }
            }
        }
}

extern "C" void kernel_launch(void* const* d_in, const int* in_sizes, int n_in,
                              void* d_out, int out_size, void* d_ws, size_t ws_size,
                              hipStream_t stream) {
    (void)in_sizes; (void)n_in;
    const float* x  = (const float*)d_in[0];
    const float* rw = (const float*)d_in[1];
    const float* w1 = (const float*)d_in[2];
    const float* b1 = (const float*)d_in[3];
    const float* w2 = (const float*)d_in[4];
    const float* b2 = (const float*)d_in[5];
    float* out = (float*)d_out;

    char* ws = (char*)d_ws;
    size_t off = 0;
    auto alloc = [&](size_t bytes) -> char* {
        char* p = ws + off;
        off = (off + bytes + 255) & ~(size_t)255;
        return p;
    };

    float* scores = (float*)alloc((size_t)BATCH * NEXP * SEQ * 4);
    int*   sel    = (int*)  alloc((size_t)BATCH * NEXP * CAPC * 4);
    float* gate   = (float*)alloc((size_t)BATCH * NEXP * CAPC * 4);
    size_t common = off;

    hipMemsetAsync(d_out, 0, (size_t)out_size * sizeof(float), stream);
    router_kernel<<<BATCH * SEQ, 64, 0, stream>>>(x, rw, scores);
    topk_kernel<<<BATCH * NEXP * 8, 256, 0, stream>>>(scores, sel, gate);

    // ---- choose N-chunking factor C: footprint = common + A1 + 528MB/C -----
    const size_t A1B = (size_t)MTOT * DIMD * 2;          // one of A1 hi/lo
    int C = 0;
    for (int c = 1; c <= 8; c <<= 1) {
        size_t w1c = (size_t)NEXP * (HIDN / c) * DIMD * 2;
        size_t w2c = (size_t)NEXP * DIMD * (HIDN / c) * 2;
        size_t hc  = (size_t)MTOT * (HIDN / c) * 2;
        size_t need = common + 2 * A1B + 2 * w1c + 2 * w2c + 2 * hc + (8u << 20);
        if (need <= ws_size) { C = c; break; }
    }

    if (C) {
        const int HN = HIDN / C;                          // chunk width (>=512)
        unsigned short* A1h = (unsigned short*)alloc(A1B);
        unsigned short* A1l = (unsigned short*)alloc(A1B);
        size_t W1CB = (size_t)NEXP * HN * DIMD * 2;
        size_t W2CB = (size_t)NEXP * DIMD * HN * 2;
        size_t HCB  = (size_t)MTOT * HN * 2;
        unsigned short* W1h = (unsigned short*)alloc(W1CB);
        unsigned short* W1l = (unsigned short*)alloc(W1CB);
        unsigned short* W2h = (unsigned short*)alloc(W2CB);
        unsigned short* W2l = (unsigned short*)alloc(W2CB);
        unsigned short* Hh  = (unsigned short*)alloc(HCB);
        unsigned short* Hl  = (unsigned short*)alloc(HCB);

        gather_kernel<<<MTOT, 256, 0, stream>>>(x, sel, A1h, A1l, 0);

        for (int c = 0; c < C; ++c) {
            // w1 chunk: [1024 x HN] slice at n0 = c*HN -> [HN x 1024] per expert
            convT_kernel<<<dim3(DIMD / 64, HN / 64, NEXP), 256, 0, stream>>>(
                w1, W1h, W1l, HIDN, (size_t)DIMD * HIDN, 0, c * HN, DIMD, HN);
            gemm1_mfma<<<dim3(MTILES, HN / 128), 256, 0, stream>>>(
                A1h, A1l, W1h, W1l, b1, Hh, Hl, 0, (size_t)HN * DIMD, c * HN, HN);
            // w2 chunk: rows [c*HN, c*HN+HN) x 1024 -> [1024 x HN] per expert
            convT_kernel<<<dim3(HN / 64, DIMD / 64, NEXP), 256, 0, stream>>>(
                w2, W2h, W2l, DIMD, (size_t)HIDN * DIMD, c * HN, 0, HN, DIMD);
            gemm2_mfma<<<dim3(MTILES, DIMD / 128), 256, 0, stream>>>(
                Hh, Hl, W2h, W2l, (c == 0) ? b2 : nullptr, sel, gate, out,
                0, (size_t)DIMD * HN, HN);
        }
    } else {
        // ---- per-expert fallback (~78 MB) ----
        const size_t A1E = (size_t)RPEX * DIMD * 2;
        const size_t WE  = (size_t)HIDN * DIMD * 2;
        const size_t HE  = (size_t)RPEX * HIDN * 2;
        unsigned short* A1h = (unsigned short*)alloc(A1E);
        unsigned short* A1l = (unsigned short*)alloc(A1E);
        unsigned short* W1h = (unsigned short*)alloc(WE);
        unsigned short* W1l = (unsigned short*)alloc(WE);
        unsigned short* W2h = (unsigned short*)alloc(WE);
        unsigned short* W2l = (unsigned short*)alloc(WE);
        unsigned short* Hh  = (unsigned short*)alloc(HE);
        unsigned short* Hl  = (unsigned short*)alloc(HE);

        for (int e = 0; e < NEXP; ++e) {
            gather_kernel<<<RPEX, 256, 0, stream>>>(x, sel, A1h, A1l, e * RPEX);
            convT_kernel<<<dim3(DIMD / 64, HIDN / 64, 1), 256, 0, stream>>>(
                w1 + (size_t)e * DIMD * HIDN, W1h, W1l, HIDN, 0, 0, 0, DIMD, HIDN);
            gemm1_mfma<<<dim3(TPEX, HIDN / 128), 256, 0, stream>>>(
                A1h, A1l, W1h, W1l, b1, Hh, Hl, e * TPEX, 0, 0, HIDN);
            convT_kernel<<<dim3(HIDN / 64, DIMD / 64, 1), 256, 0, stream>>>(
                w2 + (size_t)e * HIDN * DIMD, W2h, W2l, DIMD, 0, 0, 0, HIDN, DIMD);
            gemm2_mfma<<<dim3(TPEX, DIMD / 128), 256, 0, stream>>>(
                Hh, Hl, W2h, W2l, b2, sel, gate, out, e * TPEX, 0, HIDN);
        }
    }
}

// Round 5
// 1304.626 us; speedup vs baseline: 6.3280x; 1.1411x over previous
//
#include <hip/hip_runtime.h>
#include <cstdint>

#define DIMD  1024
#define NEXP  8
#define HIDN  4096
#define BATCH 4
#define SEQ   2048
#define CAPC  513                  // int(2048*2.0/8)+1
#define RPEX  2176                 // rows per expert, padded to 17*128
#define TPEX  17                   // 128-row tiles per expert
#define MTOT  (NEXP * RPEX)        // 17408
#define MTILES (MTOT / 128)        // 136

typedef __bf16 bf16x8 __attribute__((ext_vector_type(8)));
typedef float  f32x4  __attribute__((ext_vector_type(4)));

__device__ __forceinline__ unsigned short f2bf(float f) {
    unsigned u = __float_as_uint(f);
    unsigned r = (u + 0x7FFFu + ((u >> 16) & 1u)) >> 16;
    return (unsigned short)r;
}
__device__ __forceinline__ void split1(float f, unsigned short& h, unsigned short& l) {
    h = f2bf(f);
    float hf = __uint_as_float(((unsigned)h) << 16);
    l = f2bf(f - hf);
}

// bijective XCD-chunked swizzle (m204) + y-fastest order for L2/L3 locality
__device__ __forceinline__ void swz_xy(int nY, int& bx, int& by) {
    int G = gridDim.x;
    int q = G >> 3, r = G & 7;
    int xcd = blockIdx.x & 7, pos = blockIdx.x >> 3;
    int wg = (xcd < r ? xcd * (q + 1) : r * (q + 1) + (xcd - r) * q) + pos;
    bx = wg / nY; by = wg - bx * nY;
}

// ---------------- router: scores_t [B][E][S] = softmax over E ----------------
__global__ __launch_bounds__(64)
void router_kernel(const float* __restrict__ x, const float* __restrict__ rw,
                   float* __restrict__ scores) {
    int token = blockIdx.x;
    int lane  = threadIdx.x;
    const float4* xr = reinterpret_cast<const float4*>(x + (size_t)token * DIMD);
    float4 xv[4];
#pragma unroll
    for (int j = 0; j < 4; ++j) xv[j] = xr[lane * 4 + j];
    float acc[NEXP];
#pragma unroll
    for (int e = 0; e < NEXP; ++e) {
        const float4* wr = reinterpret_cast<const float4*>(rw + (size_t)e * DIMD);
        float a = 0.f;
#pragma unroll
        for (int j = 0; j < 4; ++j) {
            float4 wv = wr[lane * 4 + j];
            a += xv[j].x * wv.x; a += xv[j].y * wv.y;
            a += xv[j].z * wv.z; a += xv[j].w * wv.w;
        }
#pragma unroll
        for (int off = 32; off > 0; off >>= 1) a += __shfl_xor(a, off);
        acc[e] = a;
    }
    float m = acc[0];
#pragma unroll
    for (int e = 1; e < NEXP; ++e) m = fmaxf(m, acc[e]);
    float s = 0.f;
#pragma unroll
    for (int e = 0; e < NEXP; ++e) { acc[e] = expf(acc[e] - m); s += acc[e]; }
    float inv = 1.f / s;
    if (lane == 0) {
        int b = token >> 11;
        int t = token & (SEQ - 1);
#pragma unroll
        for (int e = 0; e < NEXP; ++e)
            scores[((size_t)(b * NEXP + e)) * SEQ + t] = acc[e] * inv;
    }
}

// ------- expert-choice top-k via exact rank (stable, desc), 256 blocks -------
// also builds the token->Y-row inverse map for the combine kernel.
__global__ __launch_bounds__(256)
void topk_kernel(const float* __restrict__ scores, int* __restrict__ sel,
                 float* __restrict__ gate, int* __restrict__ cnt,
                 int* __restrict__ invmap) {
    int be    = blockIdx.x >> 3;
    int chunk = blockIdx.x & 7;
    const float* sc = scores + (size_t)be * SEQ;
    __shared__ float s_sc[SEQ];
    int t = threadIdx.x;
#pragma unroll
    for (int q = 0; q < 8; ++q) s_sc[t + q * 256] = sc[t + q * 256];
    __syncthreads();
    int i = chunk * 256 + t;
    float v = s_sc[i];
    int r = 0;
#pragma unroll 8
    for (int j = 0; j < SEQ; ++j) {
        float u = s_sc[j];
        r += (u > v) || (u == v && j < i);
    }
    if (r < CAPC) {
        sel [(size_t)be * CAPC + r] = i;
        gate[(size_t)be * CAPC + r] = v;
        int b = be >> 3, e = be & 7;
        int tok = b * SEQ + i;
        int p = atomicAdd(cnt + tok, 1);
        invmap[(size_t)tok * 8 + p] = e * RPEX + b * CAPC + r;   // Y row
    }
}

// ---------------- gather + split: A1 rows (padded) -> hi/lo bf16 -------------
__global__ __launch_bounds__(256)
void gather_kernel(const float* __restrict__ x, const int* __restrict__ sel,
                   unsigned short* __restrict__ dhi, unsigned short* __restrict__ dlo) {
    int gr = blockIdx.x;
    int e  = gr / RPEX;
    int rl = gr - e * RPEX;
    int t  = threadIdx.x;
    size_t dbase = (size_t)gr * DIMD + t * 4;
    if (rl < BATCH * CAPC) {
        int b = rl / CAPC, c = rl - b * CAPC;
        int tok = sel[(size_t)(b * NEXP + e) * CAPC + c];
        float4 v = *reinterpret_cast<const float4*>(x + ((size_t)(b * SEQ + tok)) * DIMD + t * 4);
        ushort4 h, l;
        split1(v.x, h.x, l.x); split1(v.y, h.y, l.y);
        split1(v.z, h.z, l.z); split1(v.w, h.w, l.w);
        *reinterpret_cast<ushort4*>(dhi + dbase) = h;
        *reinterpret_cast<ushort4*>(dlo + dbase) = l;
    } else {
        ushort4 z = {0, 0, 0, 0};
        *reinterpret_cast<ushort4*>(dhi + dbase) = z;
        *reinterpret_cast<ushort4*>(dlo + dbase) = z;
    }
}

// ------ weight transpose+split of a sub-block: src[k0+kLen][n0+nLen] ---------
__global__ __launch_bounds__(256)
void convT_kernel(const float* __restrict__ src, unsigned short* __restrict__ dhi,
                  unsigned short* __restrict__ dlo, int Nsrc, size_t srcEStride,
                  int k0, int n0, int kLen, int nLen) {
    int e = blockIdx.z;
    src += (size_t)e * srcEStride;
    size_t dstE = (size_t)e * kLen * nLen;
    dhi += dstE; dlo += dstE;
    int kb = blockIdx.x * 64, nb = blockIdx.y * 64;
    __shared__ float T[64][65];
    int t = threadIdx.x;
    for (int i = t; i < 1024; i += 256) {
        int r = i >> 4, c4 = (i & 15) * 4;
        float4 v = *reinterpret_cast<const float4*>(
            src + (size_t)(k0 + kb + r) * Nsrc + n0 + nb + c4);
        T[r][c4 + 0] = v.x; T[r][c4 + 1] = v.y; T[r][c4 + 2] = v.z; T[r][c4 + 3] = v.w;
    }
    __syncthreads();
    for (int i = t; i < 1024; i += 256) {
        int n = i >> 4, kc = (i & 15) * 4;
        ushort4 h, l;
        split1(T[kc + 0][n], h.x, l.x); split1(T[kc + 1][n], h.y, l.y);
        split1(T[kc + 2][n], h.z, l.z); split1(T[kc + 3][n], h.w, l.w);
        size_t o = (size_t)(nb + n) * kLen + kb + kc;
        *reinterpret_cast<ushort4*>(dhi + o) = h;
        *reinterpret_cast<ushort4*>(dlo + o) = l;
    }
}

// ======================= split-bf16 3-pass MFMA GEMMs ========================
#define GEMM_STAGE_DECLS \
    __shared__ __align__(16) unsigned short As_h[128][40]; \
    __shared__ __align__(16) unsigned short As_l[128][40]; \
    __shared__ __align__(16) unsigned short Bs_h[128][40]; \
    __shared__ __align__(16) unsigned short Bs_l[128][40];

__device__ __forceinline__ void mfma_triple(f32x4 acc[4][4], const bf16x8 ah[4],
                                            const bf16x8 al[4], const bf16x8 bh[4],
                                            const bf16x8 bl[4]) {
#pragma unroll
    for (int m = 0; m < 4; ++m)
#pragma unroll
        for (int n = 0; n < 4; ++n)
            acc[m][n] = __builtin_amdgcn_mfma_f32_16x16x32_bf16(ah[m], bh[n], acc[m][n], 0, 0, 0);
#pragma unroll
    for (int m = 0; m < 4; ++m)
#pragma unroll
        for (int n = 0; n < 4; ++n)
            acc[m][n] = __builtin_amdgcn_mfma_f32_16x16x32_bf16(ah[m], bl[n], acc[m][n], 0, 0, 0);
#pragma unroll
    for (int m = 0; m < 4; ++m)
#pragma unroll
        for (int n = 0; n < 4; ++n)
            acc[m][n] = __builtin_amdgcn_mfma_f32_16x16x32_bf16(al[m], bh[n], acc[m][n], 0, 0, 0);
}

#define LOADK1(k0c) do { \
    rAh0 = *(const uint4*)(Ahi + a0 + (k0c) + kc0); rAh1 = *(const uint4*)(Ahi + a1 + (k0c) + kc0); \
    rAl0 = *(const uint4*)(Alo + a0 + (k0c) + kc0); rAl1 = *(const uint4*)(Alo + a1 + (k0c) + kc0); \
    rBh0 = *(const uint4*)(Bh  + b0 + (k0c) + kc0); rBh1 = *(const uint4*)(Bh  + b1o + (k0c) + kc0); \
    rBl0 = *(const uint4*)(Bl  + b0 + (k0c) + kc0); rBl1 = *(const uint4*)(Bl  + b1o + (k0c) + kc0); } while (0)

// -------- GEMM1: H[:,chunk] = gelu(A1 @ W1c^T + b1[nbias0+...]), K=1024 ------
__global__ __launch_bounds__(256)
void gemm1_mfma(const unsigned short* __restrict__ Ahi, const unsigned short* __restrict__ Alo,
                const unsigned short* __restrict__ Whi, const unsigned short* __restrict__ Wlo,
                const float* __restrict__ bias,
                unsigned short* __restrict__ Hhi, unsigned short* __restrict__ Hlo,
                size_t wstride, int nbias0, int ldh, int nY) {
    const int K = DIMD;
    int bx, by; swz_xy(nY, bx, by);
    int bn = by * 128;
    int e = bx / TPEX;
    const unsigned short* Bh = Whi + (size_t)e * wstride;
    const unsigned short* Bl = Wlo + (size_t)e * wstride;
    int t = threadIdx.x;
    int l = t & 63, wid = t >> 6;
    int wr = wid >> 1, wc = wid & 1;
    int grp = l >> 4, li = l & 15;

    GEMM_STAGE_DECLS

    int srow = t >> 2, scg = t & 3, kc0 = scg * 8;
    size_t a0 = (size_t)(bx * 128 + srow) * K;
    size_t a1 = (size_t)(bx * 128 + srow + 64) * K;
    size_t b0 = (size_t)(bn + srow) * K;
    size_t b1o = (size_t)(bn + srow + 64) * K;

    f32x4 acc[4][4];
#pragma unroll
    for (int m = 0; m < 4; ++m)
#pragma unroll
        for (int n = 0; n < 4; ++n) { f32x4 z = {0.f, 0.f, 0.f, 0.f}; acc[m][n] = z; }

    uint4 rAh0, rAh1, rAl0, rAl1, rBh0, rBh1, rBl0, rBl1;
    LOADK1(0);
    for (int kt = 0; kt < K; kt += 32) {
        __syncthreads();
        *(uint4*)&As_h[srow][kc0] = rAh0; *(uint4*)&As_h[srow + 64][kc0] = rAh1;
        *(uint4*)&As_l[srow][kc0] = rAl0; *(uint4*)&As_l[srow + 64][kc0] = rAl1;
        *(uint4*)&Bs_h[srow][kc0] = rBh0; *(uint4*)&Bs_h[srow + 64][kc0] = rBh1;
        *(uint4*)&Bs_l[srow][kc0] = rBl0; *(uint4*)&Bs_l[srow + 64][kc0] = rBl1;
        __syncthreads();
        if (kt + 32 < K) LOADK1(kt + 32);
        bf16x8 ah[4], al[4], bh[4], bl[4];
#pragma unroll
        for (int m = 0; m < 4; ++m) {
            ah[m] = *(const bf16x8*)&As_h[wr * 64 + m * 16 + li][grp * 8];
            al[m] = *(const bf16x8*)&As_l[wr * 64 + m * 16 + li][grp * 8];
        }
#pragma unroll
        for (int n = 0; n < 4; ++n) {
            bh[n] = *(const bf16x8*)&Bs_h[wc * 64 + n * 16 + li][grp * 8];
            bl[n] = *(const bf16x8*)&Bs_l[wc * 64 + n * 16 + li][grp * 8];
        }
        mfma_triple(acc, ah, al, bh, bl);
    }

    int hr0 = bx * 128 + wr * 64;
    int cb = bn + wc * 64;
#pragma unroll
    for (int m = 0; m < 4; ++m)
#pragma unroll
        for (int q = 0; q < 4; ++q) {
            int row = hr0 + m * 16 + grp * 4 + q;
#pragma unroll
            for (int n = 0; n < 4; ++n) {
                int col = cb + n * 16 + li;
                float v = acc[m][n][q] + bias[(size_t)e * HIDN + nbias0 + col];
                float g = 0.5f * v * (1.0f + erff(v * 0.70710678118654752f));
                unsigned short hh, hl;
                split1(g, hh, hl);
                Hhi[(size_t)row * ldh + col] = hh;
                Hlo[(size_t)row * ldh + col] = hl;
            }
        }
}

// -------- GEMM2: Y[row] (+)= gate*(Hc @ W2c^T [+ b2]) dense, no atomics ------
__global__ __launch_bounds__(256)
void gemm2_mfma(const unsigned short* __restrict__ Ahi, const unsigned short* __restrict__ Alo,
                const unsigned short* __restrict__ Whi, const unsigned short* __restrict__ Wlo,
                const float* __restrict__ bias, const float* __restrict__ gate,
                float* __restrict__ Y, size_t wstride, int K, int nY) {
    int bx, by; swz_xy(nY, bx, by);
    int bn = by * 128;
    int e = bx / TPEX;
    int rbase_e = (bx - e * TPEX) * 128;
    const unsigned short* Bh = Whi + (size_t)e * wstride;
    const unsigned short* Bl = Wlo + (size_t)e * wstride;
    int t = threadIdx.x;
    int l = t & 63, wid = t >> 6;
    int wr = wid >> 1, wc = wid & 1;
    int grp = l >> 4, li = l & 15;

    GEMM_STAGE_DECLS

    int srow = t >> 2, scg = t & 3, kc0 = scg * 8;
    size_t a0 = (size_t)(bx * 128 + srow) * K;
    size_t a1 = (size_t)(bx * 128 + srow + 64) * K;
    size_t b0 = (size_t)(bn + srow) * K;
    size_t b1o = (size_t)(bn + srow + 64) * K;

    f32x4 acc[4][4];
#pragma unroll
    for (int m = 0; m < 4; ++m)
#pragma unroll
        for (int n = 0; n < 4; ++n) { f32x4 z = {0.f, 0.f, 0.f, 0.f}; acc[m][n] = z; }

    uint4 rAh0, rAh1, rAl0, rAl1, rBh0, rBh1, rBl0, rBl1;
    LOADK1(0);
    for (int kt = 0; kt < K; kt += 32) {
        __syncthreads();
        *(uint4*)&As_h[srow][kc0] = rAh0; *(uint4*)&As_h[srow + 64][kc0] = rAh1;
        *(uint4*)&As_l[srow][kc0] = rAl0; *(uint4*)&As_l[srow + 64][kc0] = rAl1;
        *(uint4*)&Bs_h[srow][kc0] = rBh0; *(uint4*)&Bs_h[srow + 64][kc0] = rBh1;
        *(uint4*)&Bs_l[srow][kc0] = rBl0; *(uint4*)&Bs_l[srow + 64][kc0] = rBl1;
        __syncthreads();
        if (kt + 32 < K) LOADK1(kt + 32);
        bf16x8 ah[4], al[4], bh[4], bl[4];
#pragma unroll
        for (int m = 0; m < 4; ++m) {
            ah[m] = *(const bf16x8*)&As_h[wr * 64 + m * 16 + li][grp * 8];
            al[m] = *(const bf16x8*)&As_l[wr * 64 + m * 16 + li][grp * 8];
        }
#pragma unroll
        for (int n = 0; n < 4; ++n) {
            bh[n] = *(const bf16x8*)&Bs_h[wc * 64 + n * 16 + li][grp * 8];
            bl[n] = *(const bf16x8*)&Bs_l[wc * 64 + n * 16 + li][grp * 8];
        }
        mfma_triple(acc, ah, al, bh, bl);
    }

    int cb = bn + wc * 64;
#pragma unroll
    for (int m = 0; m < 4; ++m)
#pragma unroll
        for (int q = 0; q < 4; ++q) {
            int off = wr * 64 + m * 16 + grp * 4 + q;
            int rloc = rbase_e + off;
            if (rloc < BATCH * CAPC) {
                int b = rloc / CAPC, c = rloc - b * CAPC;
                float g = gate[(size_t)(b * NEXP + e) * CAPC + c];
                size_t grow = (size_t)bx * 128 + off;
#pragma unroll
                for (int n = 0; n < 4; ++n) {
                    int col = cb + n * 16 + li;
                    float v = acc[m][n][q];
                    size_t yo = grow * DIMD + col;
                    if (bias) Y[yo] = g * (v + bias[(size_t)e * DIMD + col]);
                    else      Y[yo] = Y[yo] + g * v;
                }
            }
        }
}

// -------- combine: out[b,s,:] = sum over <=8 gated Y rows (no atomics) -------
__global__ __launch_bounds__(64)
void combine_kernel(const float* __restrict__ Y, const int* __restrict__ cnt,
                    const int* __restrict__ invmap, float* __restrict__ out) {
    int tok = blockIdx.x;
    int lane = threadIdx.x;
    int n = cnt[tok];
    f32x4 acc[4];
#pragma unroll
    for (int q = 0; q < 4; ++q) { f32x4 z = {0.f, 0.f, 0.f, 0.f}; acc[q] = z; }
#pragma unroll
    for (int j = 0; j < 8; ++j) {
        if (j < n) {
            int row = invmap[(size_t)tok * 8 + j];
            const f32x4* yr = reinterpret_cast<const f32x4*>(Y + (size_t)row * DIMD);
#pragma unroll
            for (int q = 0; q < 4; ++q) acc[q] += yr[q * 64 + lane];
        }
    }
    f32x4* op = reinterpret_cast<f32x4*>(out + (size_t)tok * DIMD);
#pragma unroll
    for (int q = 0; q < 4; ++q) op[q * 64 + lane] = acc[q];
}

extern "C" void kernel_launch(void* const* d_in, const int* in_sizes, int n_in,
                              void* d_out, int out_size, void* d_ws, size_t ws_size,
                              hipStream_t stream) {
    (void)in_sizes; (void)n_in; (void)out_size;
    const float* x  = (const float*)d_in[0];
    const float* rw = (const float*)d_in[1];
    const float* w1 = (const float*)d_in[2];
    const float* b1 = (const float*)d_in[3];
    const float* w2 = (const float*)d_in[4];
    const float* b2 = (const float*)d_in[5];
    float* out = (float*)d_out;

    char* ws = (char*)d_ws;
    size_t off = 0;
    auto alloc = [&](size_t bytes) -> char* {
        char* p = ws + off;
        off = (off + bytes + 255) & ~(size_t)255;
        return p;
    };

    float* scores = (float*)alloc((size_t)BATCH * NEXP * SEQ * 4);
    int*   sel    = (int*)  alloc((size_t)BATCH * NEXP * CAPC * 4);
    float* gate   = (float*)alloc((size_t)BATCH * NEXP * CAPC * 4);
    int*   cnt    = (int*)  alloc((size_t)BATCH * SEQ * 4);
    int*   invmap = (int*)  alloc((size_t)BATCH * SEQ * 8 * 4);
    float* Y      = (float*)alloc((size_t)MTOT * DIMD * 4);
    size_t common = off;

    // ---- choose N-chunk factor C (footprint = common + A1 + (268+285)/C MB) --
    const size_t A1B = (size_t)MTOT * DIMD * 2;          // one of A1 hi/lo
    int C = 8;
    for (int c = 2; c <= 8; c <<= 1) {
        size_t wc = (size_t)NEXP * (HIDN / c) * DIMD * 2;   // one array
        size_t hc = (size_t)MTOT * (HIDN / c) * 2;          // one array
        size_t need = common + 2 * A1B + 4 * wc + 2 * hc + (8u << 20);
        if (need <= ws_size) { C = c; break; }
    }
    const int HN = HIDN / C;

    unsigned short* A1h = (unsigned short*)alloc(A1B);
    unsigned short* A1l = (unsigned short*)alloc(A1B);
    size_t WCB = (size_t)NEXP * HN * DIMD * 2;
    size_t HCB = (size_t)MTOT * HN * 2;
    unsigned short* W1h = (unsigned short*)alloc(WCB);
    unsigned short* W1l = (unsigned short*)alloc(WCB);
    unsigned short* W2h = (unsigned short*)alloc(WCB);
    unsigned short* W2l = (unsigned short*)alloc(WCB);
    unsigned short* Hh  = (unsigned short*)alloc(HCB);
    unsigned short* Hl  = (unsigned short*)alloc(HCB);

    hipMemsetAsync(cnt, 0, (size_t)BATCH * SEQ * 4, stream);
    router_kernel<<<BATCH * SEQ, 64, 0, stream>>>(x, rw, scores);
    topk_kernel<<<BATCH * NEXP * 8, 256, 0, stream>>>(scores, sel, gate, cnt, invmap);
    gather_kernel<<<MTOT, 256, 0, stream>>>(x, sel, A1h, A1l);

    for (int c = 0; c < C; ++c) {
        convT_kernel<<<dim3(DIMD / 64, HN / 64, NEXP), 256, 0, stream>>>(
            w1, W1h, W1l, HIDN, (size_t)DIMD * HIDN, 0, c * HN, DIMD, HN);
        gemm1_mfma<<<MTILES * (HN / 128), 256, 0, stream>>>(
            A1h, A1l, W1h, W1l, b1, Hh, Hl, (size_t)HN * DIMD, c * HN, HN, HN / 128);
        convT_kernel<<<dim3(HN / 64, DIMD / 64, NEXP), 256, 0, stream>>>(
            w2, W2h, W2l, DIMD, (size_t)HIDN * DIMD, c * HN, 0, HN, DIMD);
        gemm2_mfma<<<MTILES * (DIMD / 128), 256, 0, stream>>>(
            Hh, Hl, W2h, W2l, (c == 0) ? b2 : nullptr, gate, Y,
            (size_t)DIMD * HN, HN, DIMD / 128);
    }
    combine_kernel<<<BATCH * SEQ, 64, 0, stream>>>(Y, cnt, invmap, out);
}

// Round 6
// 943.239 us; speedup vs baseline: 8.7524x; 1.3831x over previous
//
#include <hip/hip_runtime.h>
#include <cstdint>

#define DIMD  1024
#define NEXP  8
#define HIDN  4096
#define BATCH 4
#define SEQ   2048
#define CAPC  513                  // int(2048*2.0/8)+1
#define RPEX  2176                 // rows per expert, padded to 17*128
#define TPEX  17                   // 128-row tiles per expert
#define MTOT  (NEXP * RPEX)        // 17408
#define MTILES (MTOT / 128)        // 136

typedef __bf16 bf16x8 __attribute__((ext_vector_type(8)));
typedef float  f32x4  __attribute__((ext_vector_type(4)));

__device__ __forceinline__ unsigned short f2bf(float f) {
    unsigned u = __float_as_uint(f);
    unsigned r = (u + 0x7FFFu + ((u >> 16) & 1u)) >> 16;
    return (unsigned short)r;
}
__device__ __forceinline__ void split1(float f, unsigned short& h, unsigned short& l) {
    h = f2bf(f);
    float hf = __uint_as_float(((unsigned)h) << 16);
    l = f2bf(f - hf);
}

// bijective XCD-chunked swizzle (m204) + y-fastest order for L2/L3 locality
__device__ __forceinline__ void swz_xy(int nY, int& bx, int& by) {
    int G = gridDim.x;
    int q = G >> 3, r = G & 7;
    int xcd = blockIdx.x & 7, pos = blockIdx.x >> 3;
    int wg = (xcd < r ? xcd * (q + 1) : r * (q + 1) + (xcd - r) * q) + pos;
    bx = wg / nY; by = wg - bx * nY;
}

// ---------------- router: scores_t [B][E][S] = softmax over E ----------------
__global__ __launch_bounds__(64)
void router_kernel(const float* __restrict__ x, const float* __restrict__ rw,
                   float* __restrict__ scores) {
    int token = blockIdx.x;
    int lane  = threadIdx.x;
    const float4* xr = reinterpret_cast<const float4*>(x + (size_t)token * DIMD);
    float4 xv[4];
#pragma unroll
    for (int j = 0; j < 4; ++j) xv[j] = xr[lane * 4 + j];
    float acc[NEXP];
#pragma unroll
    for (int e = 0; e < NEXP; ++e) {
        const float4* wr = reinterpret_cast<const float4*>(rw + (size_t)e * DIMD);
        float a = 0.f;
#pragma unroll
        for (int j = 0; j < 4; ++j) {
            float4 wv = wr[lane * 4 + j];
            a += xv[j].x * wv.x; a += xv[j].y * wv.y;
            a += xv[j].z * wv.z; a += xv[j].w * wv.w;
        }
#pragma unroll
        for (int off = 32; off > 0; off >>= 1) a += __shfl_xor(a, off);
        acc[e] = a;
    }
    float m = acc[0];
#pragma unroll
    for (int e = 1; e < NEXP; ++e) m = fmaxf(m, acc[e]);
    float s = 0.f;
#pragma unroll
    for (int e = 0; e < NEXP; ++e) { acc[e] = expf(acc[e] - m); s += acc[e]; }
    float inv = 1.f / s;
    if (lane == 0) {
        int b = token >> 11;
        int t = token & (SEQ - 1);
#pragma unroll
        for (int e = 0; e < NEXP; ++e)
            scores[((size_t)(b * NEXP + e)) * SEQ + t] = acc[e] * inv;
    }
}

// ------- expert-choice top-k via exact rank (stable, desc), 256 blocks -------
__global__ __launch_bounds__(256)
void topk_kernel(const float* __restrict__ scores, int* __restrict__ sel,
                 float* __restrict__ gate, int* __restrict__ cnt,
                 int* __restrict__ invmap) {
    int be    = blockIdx.x >> 3;
    int chunk = blockIdx.x & 7;
    const float* sc = scores + (size_t)be * SEQ;
    __shared__ float s_sc[SEQ];
    int t = threadIdx.x;
#pragma unroll
    for (int q = 0; q < 8; ++q) s_sc[t + q * 256] = sc[t + q * 256];
    __syncthreads();
    int i = chunk * 256 + t;
    float v = s_sc[i];
    int r = 0;
#pragma unroll 8
    for (int j = 0; j < SEQ; ++j) {
        float u = s_sc[j];
        r += (u > v) || (u == v && j < i);
    }
    if (r < CAPC) {
        sel [(size_t)be * CAPC + r] = i;
        gate[(size_t)be * CAPC + r] = v;
        int b = be >> 3, e = be & 7;
        int tok = b * SEQ + i;
        int p = atomicAdd(cnt + tok, 1);
        invmap[(size_t)tok * 8 + p] = e * RPEX + b * CAPC + r;   // Y row
    }
}

// ---------------- gather: A1 rows (padded) -> bf16 (hi only) -----------------
__global__ __launch_bounds__(256)
void gather_kernel(const float* __restrict__ x, const int* __restrict__ sel,
                   unsigned short* __restrict__ dhi) {
    int gr = blockIdx.x;
    int e  = gr / RPEX;
    int rl = gr - e * RPEX;
    int t  = threadIdx.x;
    size_t dbase = (size_t)gr * DIMD + t * 4;
    if (rl < BATCH * CAPC) {
        int b = rl / CAPC, c = rl - b * CAPC;
        int tok = sel[(size_t)(b * NEXP + e) * CAPC + c];
        float4 v = *reinterpret_cast<const float4*>(x + ((size_t)(b * SEQ + tok)) * DIMD + t * 4);
        ushort4 h;
        h.x = f2bf(v.x); h.y = f2bf(v.y); h.z = f2bf(v.z); h.w = f2bf(v.w);
        *reinterpret_cast<ushort4*>(dhi + dbase) = h;
    } else {
        ushort4 z = {0, 0, 0, 0};
        *reinterpret_cast<ushort4*>(dhi + dbase) = z;
    }
}

// ------ weight transpose+split of a sub-block: src[k0+kLen][n0+nLen] ---------
__global__ __launch_bounds__(256)
void convT_kernel(const float* __restrict__ src, unsigned short* __restrict__ dhi,
                  unsigned short* __restrict__ dlo, int Nsrc, size_t srcEStride,
                  int k0, int n0, int kLen, int nLen) {
    int e = blockIdx.z;
    src += (size_t)e * srcEStride;
    size_t dstE = (size_t)e * kLen * nLen;
    dhi += dstE; dlo += dstE;
    int kb = blockIdx.x * 64, nb = blockIdx.y * 64;
    __shared__ float T[64][65];
    int t = threadIdx.x;
    for (int i = t; i < 1024; i += 256) {
        int r = i >> 4, c4 = (i & 15) * 4;
        float4 v = *reinterpret_cast<const float4*>(
            src + (size_t)(k0 + kb + r) * Nsrc + n0 + nb + c4);
        T[r][c4 + 0] = v.x; T[r][c4 + 1] = v.y; T[r][c4 + 2] = v.z; T[r][c4 + 3] = v.w;
    }
    __syncthreads();
    for (int i = t; i < 1024; i += 256) {
        int n = i >> 4, kc = (i & 15) * 4;
        ushort4 h, l;
        split1(T[kc + 0][n], h.x, l.x); split1(T[kc + 1][n], h.y, l.y);
        split1(T[kc + 2][n], h.z, l.z); split1(T[kc + 3][n], h.w, l.w);
        size_t o = (size_t)(nb + n) * kLen + kb + kc;
        *reinterpret_cast<ushort4*>(dhi + o) = h;
        *reinterpret_cast<ushort4*>(dlo + o) = l;
    }
}

// ================== 2-pass split-bf16 MFMA GEMMs (A bf16, W hi/lo) ===========
// Tile 128x128, BK=32, 256 thr (4 waves, 64x64 each, 4x4 frags 16x16x32).
// LDS rows padded to 40 ushorts; 30 KB total -> 5 blocks/CU by LDS.
#define GEMM_STAGE_DECLS \
    __shared__ __align__(16) unsigned short As_h[128][40]; \
    __shared__ __align__(16) unsigned short Bs_h[128][40]; \
    __shared__ __align__(16) unsigned short Bs_l[128][40];

__device__ __forceinline__ void mfma_double(f32x4 acc[4][4], const bf16x8 ah[4],
                                            const bf16x8 bh[4], const bf16x8 bl[4]) {
#pragma unroll
    for (int m = 0; m < 4; ++m)
#pragma unroll
        for (int n = 0; n < 4; ++n)
            acc[m][n] = __builtin_amdgcn_mfma_f32_16x16x32_bf16(ah[m], bh[n], acc[m][n], 0, 0, 0);
#pragma unroll
    for (int m = 0; m < 4; ++m)
#pragma unroll
        for (int n = 0; n < 4; ++n)
            acc[m][n] = __builtin_amdgcn_mfma_f32_16x16x32_bf16(ah[m], bl[n], acc[m][n], 0, 0, 0);
}

#define LOADK1(k0c) do { \
    rAh0 = *(const uint4*)(Ahi + a0 + (k0c) + kc0); rAh1 = *(const uint4*)(Ahi + a1 + (k0c) + kc0); \
    rBh0 = *(const uint4*)(Bh  + b0 + (k0c) + kc0); rBh1 = *(const uint4*)(Bh  + b1o + (k0c) + kc0); \
    rBl0 = *(const uint4*)(Bl  + b0 + (k0c) + kc0); rBl1 = *(const uint4*)(Bl  + b1o + (k0c) + kc0); } while (0)

#define STAGEK1() do { \
    *(uint4*)&As_h[srow][kc0] = rAh0; *(uint4*)&As_h[srow + 64][kc0] = rAh1; \
    *(uint4*)&Bs_h[srow][kc0] = rBh0; *(uint4*)&Bs_h[srow + 64][kc0] = rBh1; \
    *(uint4*)&Bs_l[srow][kc0] = rBl0; *(uint4*)&Bs_l[srow + 64][kc0] = rBl1; } while (0)

#define FRAG_READS() \
    bf16x8 ah[4], bh[4], bl[4]; \
    _Pragma("unroll") \
    for (int m = 0; m < 4; ++m) \
        ah[m] = *(const bf16x8*)&As_h[wr * 64 + m * 16 + li][grp * 8]; \
    _Pragma("unroll") \
    for (int n = 0; n < 4; ++n) { \
        bh[n] = *(const bf16x8*)&Bs_h[wc * 64 + n * 16 + li][grp * 8]; \
        bl[n] = *(const bf16x8*)&Bs_l[wc * 64 + n * 16 + li][grp * 8]; \
    }

// -------- GEMM1: H[:,chunk] = gelu(A1 @ W1c^T + b1[nbias0+...]), K=1024 ------
__global__ __launch_bounds__(256)
void gemm1_mfma(const unsigned short* __restrict__ Ahi,
                const unsigned short* __restrict__ Whi, const unsigned short* __restrict__ Wlo,
                const float* __restrict__ bias, unsigned short* __restrict__ Hhi,
                size_t wstride, int nbias0, int ldh, int nY) {
    const int K = DIMD;
    int bx, by; swz_xy(nY, bx, by);
    int bn = by * 128;
    int e = bx / TPEX;
    const unsigned short* Bh = Whi + (size_t)e * wstride;
    const unsigned short* Bl = Wlo + (size_t)e * wstride;
    int t = threadIdx.x;
    int l = t & 63, wid = t >> 6;
    int wr = wid >> 1, wc = wid & 1;
    int grp = l >> 4, li = l & 15;

    GEMM_STAGE_DECLS

    int srow = t >> 2, scg = t & 3, kc0 = scg * 8;
    size_t a0 = (size_t)(bx * 128 + srow) * K;
    size_t a1 = (size_t)(bx * 128 + srow + 64) * K;
    size_t b0 = (size_t)(bn + srow) * K;
    size_t b1o = (size_t)(bn + srow + 64) * K;

    f32x4 acc[4][4];
#pragma unroll
    for (int m = 0; m < 4; ++m)
#pragma unroll
        for (int n = 0; n < 4; ++n) { f32x4 z = {0.f, 0.f, 0.f, 0.f}; acc[m][n] = z; }

    uint4 rAh0, rAh1, rBh0, rBh1, rBl0, rBl1;
    LOADK1(0);
    for (int kt = 0; kt < K; kt += 32) {
        __syncthreads();
        STAGEK1();
        __syncthreads();
        if (kt + 32 < K) LOADK1(kt + 32);
        FRAG_READS();
        mfma_double(acc, ah, bh, bl);
    }

    int hr0 = bx * 128 + wr * 64;
    int cb = bn + wc * 64;
#pragma unroll
    for (int m = 0; m < 4; ++m)
#pragma unroll
        for (int q = 0; q < 4; ++q) {
            int row = hr0 + m * 16 + grp * 4 + q;
#pragma unroll
            for (int n = 0; n < 4; ++n) {
                int col = cb + n * 16 + li;
                float v = acc[m][n][q] + bias[(size_t)e * HIDN + nbias0 + col];
                float g = 0.5f * v * (1.0f + erff(v * 0.70710678118654752f));
                Hhi[(size_t)row * ldh + col] = f2bf(g);
            }
        }
}

// -------- GEMM2: Y[row] (+)= gate*(Hc @ W2c^T [+ b2]) dense, no atomics ------
__global__ __launch_bounds__(256)
void gemm2_mfma(const unsigned short* __restrict__ Ahi,
                const unsigned short* __restrict__ Whi, const unsigned short* __restrict__ Wlo,
                const float* __restrict__ bias, const float* __restrict__ gate,
                float* __restrict__ Y, size_t wstride, int K, int nY) {
    int bx, by; swz_xy(nY, bx, by);
    int bn = by * 128;
    int e = bx / TPEX;
    int rbase_e = (bx - e * TPEX) * 128;
    const unsigned short* Bh = Whi + (size_t)e * wstride;
    const unsigned short* Bl = Wlo + (size_t)e * wstride;
    int t = threadIdx.x;
    int l = t & 63, wid = t >> 6;
    int wr = wid >> 1, wc = wid & 1;
    int grp = l >> 4, li = l & 15;

    GEMM_STAGE_DECLS

    int srow = t >> 2, scg = t & 3, kc0 = scg * 8;
    size_t a0 = (size_t)(bx * 128 + srow) * K;
    size_t a1 = (size_t)(bx * 128 + srow + 64) * K;
    size_t b0 = (size_t)(bn + srow) * K;
    size_t b1o = (size_t)(bn + srow + 64) * K;

    f32x4 acc[4][4];
#pragma unroll
    for (int m = 0; m < 4; ++m)
#pragma unroll
        for (int n = 0; n < 4; ++n) { f32x4 z = {0.f, 0.f, 0.f, 0.f}; acc[m][n] = z; }

    uint4 rAh0, rAh1, rBh0, rBh1, rBl0, rBl1;
    LOADK1(0);
    for (int kt = 0; kt < K; kt += 32) {
        __syncthreads();
        STAGEK1();
        __syncthreads();
        if (kt + 32 < K) LOADK1(kt + 32);
        FRAG_READS();
        mfma_double(acc, ah, bh, bl);
    }

    int cb = bn + wc * 64;
#pragma unroll
    for (int m = 0; m < 4; ++m)
#pragma unroll
        for (int q = 0; q < 4; ++q) {
            int off = wr * 64 + m * 16 + grp * 4 + q;
            int rloc = rbase_e + off;
            if (rloc < BATCH * CAPC) {
                int b = rloc / CAPC, c = rloc - b * CAPC;
                float g = gate[(size_t)(b * NEXP + e) * CAPC + c];
                size_t grow = (size_t)bx * 128 + off;
#pragma unroll
                for (int n = 0; n < 4; ++n) {
                    int col = cb + n * 16 + li;
                    float v = acc[m][n][q];
                    size_t yo = grow * DIMD + col;
                    if (bias) Y[yo] = g * (v + bias[(size_t)e * DIMD + col]);
                    else      Y[yo] = Y[yo] + g * v;
                }
            }
        }
}

// -------- combine: out[b,s,:] = sum over <=8 gated Y rows (no atomics) -------
__global__ __launch_bounds__(64)
void combine_kernel(const float* __restrict__ Y, const int* __restrict__ cnt,
                    const int* __restrict__ invmap, float* __restrict__ out) {
    int tok = blockIdx.x;
    int lane = threadIdx.x;
    int n = cnt[tok];
    f32x4 acc[4];
#pragma unroll
    for (int q = 0; q < 4; ++q) { f32x4 z = {0.f, 0.f, 0.f, 0.f}; acc[q] = z; }
#pragma unroll
    for (int j = 0; j < 8; ++j) {
        if (j < n) {
            int row = invmap[(size_t)tok * 8 + j];
            const f32x4* yr = reinterpret_cast<const f32x4*>(Y + (size_t)row * DIMD);
#pragma unroll
            for (int q = 0; q < 4; ++q) acc[q] += yr[q * 64 + lane];
        }
    }
    f32x4* op = reinterpret_cast<f32x4*>(out + (size_t)tok * DIMD);
#pragma unroll
    for (int q = 0; q < 4; ++q) op[q * 64 + lane] = acc[q];
}

extern "C" void kernel_launch(void* const* d_in, const int* in_sizes, int n_in,
                              void* d_out, int out_size, void* d_ws, size_t ws_size,
                              hipStream_t stream) {
    (void)in_sizes; (void)n_in; (void)out_size;
    const float* x  = (const float*)d_in[0];
    const float* rw = (const float*)d_in[1];
    const float* w1 = (const float*)d_in[2];
    const float* b1 = (const float*)d_in[3];
    const float* w2 = (const float*)d_in[4];
    const float* b2 = (const float*)d_in[5];
    float* out = (float*)d_out;

    char* ws = (char*)d_ws;
    size_t off = 0;
    auto alloc = [&](size_t bytes) -> char* {
        char* p = ws + off;
        off = (off + bytes + 255) & ~(size_t)255;
        return p;
    };

    float* scores = (float*)alloc((size_t)BATCH * NEXP * SEQ * 4);
    int*   sel    = (int*)  alloc((size_t)BATCH * NEXP * CAPC * 4);
    float* gate   = (float*)alloc((size_t)BATCH * NEXP * CAPC * 4);
    int*   cnt    = (int*)  alloc((size_t)BATCH * SEQ * 4);
    int*   invmap = (int*)  alloc((size_t)BATCH * SEQ * 8 * 4);
    float* Y      = (float*)alloc((size_t)MTOT * DIMD * 4);
    size_t common = off;

    // ---- choose N-chunk factor C: footprint = common + A1 + (268+143)/C MB --
    const size_t A1B = (size_t)MTOT * DIMD * 2;          // A1 bf16 (hi only)
    int C = 8;
    for (int c = 1; c <= 8; c <<= 1) {
        size_t wc = (size_t)NEXP * (HIDN / c) * DIMD * 2;   // one of 4 W arrays
        size_t hc = (size_t)MTOT * (HIDN / c) * 2;          // H bf16 (hi only)
        size_t need = common + A1B + 4 * wc + hc + (8u << 20);
        if (need <= ws_size) { C = c; break; }
    }
    const int HN = HIDN / C;

    unsigned short* A1h = (unsigned short*)alloc(A1B);
    size_t WCB = (size_t)NEXP * HN * DIMD * 2;
    size_t HCB = (size_t)MTOT * HN * 2;
    unsigned short* W1h = (unsigned short*)alloc(WCB);
    unsigned short* W1l = (unsigned short*)alloc(WCB);
    unsigned short* W2h = (unsigned short*)alloc(WCB);
    unsigned short* W2l = (unsigned short*)alloc(WCB);
    unsigned short* Hh  = (unsigned short*)alloc(HCB);

    hipMemsetAsync(cnt, 0, (size_t)BATCH * SEQ * 4, stream);
    router_kernel<<<BATCH * SEQ, 64, 0, stream>>>(x, rw, scores);
    topk_kernel<<<BATCH * NEXP * 8, 256, 0, stream>>>(scores, sel, gate, cnt, invmap);
    gather_kernel<<<MTOT, 256, 0, stream>>>(x, sel, A1h);

    for (int c = 0; c < C; ++c) {
        convT_kernel<<<dim3(DIMD / 64, HN / 64, NEXP), 256, 0, stream>>>(
            w1, W1h, W1l, HIDN, (size_t)DIMD * HIDN, 0, c * HN, DIMD, HN);
        gemm1_mfma<<<MTILES * (HN / 128), 256, 0, stream>>>(
            A1h, W1h, W1l, b1, Hh, (size_t)HN * DIMD, c * HN, HN, HN / 128);
        convT_kernel<<<dim3(HN / 64, DIMD / 64, NEXP), 256, 0, stream>>>(
            w2, W2h, W2l, DIMD, (size_t)HIDN * DIMD, c * HN, 0, HN, DIMD);
        gemm2_mfma<<<MTILES * (DIMD / 128), 256, 0, stream>>>(
            Hh, W2h, W2l, (c == 0) ? b2 : nullptr, gate, Y,
            (size_t)DIMD * HN, HN, DIMD / 128);
    }
    combine_kernel<<<BATCH * SEQ, 64, 0, stream>>>(Y, cnt, invmap, out);
}

// Round 7
// 687.046 us; speedup vs baseline: 12.0161x; 1.3729x over previous
//
#include <hip/hip_runtime.h>
#include <cstdint>

#define DIMD  1024
#define NEXP  8
#define HIDN  4096
#define BATCH 4
#define SEQ   2048
#define CAPC  513                  // int(2048*2.0/8)+1
#define RPEX  2176                 // rows per expert, padded to 17*128
#define TPEX  17                   // 128-row tiles per expert
#define MTOT  (NEXP * RPEX)        // 17408
#define MTILES (MTOT / 128)        // 136

typedef __bf16 bf16x8 __attribute__((ext_vector_type(8)));
typedef float  f32x4  __attribute__((ext_vector_type(4)));

__device__ __forceinline__ unsigned short f2bf(float f) {
    unsigned u = __float_as_uint(f);
    unsigned r = (u + 0x7FFFu + ((u >> 16) & 1u)) >> 16;
    return (unsigned short)r;
}

// Within-XCD supercolumn traversal. Grid = 136 * nY, 136 = 8 XCDs * 17 bx.
// Each XCD owns one expert's 17 m-tiles. Walk: supercol of GY y-tiles ->
// all 17 bx -> GY inner. Keeps W-slice (GY tiles) + current A-tile L2-resident.
__device__ __forceinline__ void swz_grp(int GY, int& bx, int& by) {
    int xcd = blockIdx.x & 7, pos = blockIdx.x >> 3;
    int tps = TPEX * GY;
    int sc = pos / tps, rem = pos - sc * tps;
    int bxl = rem / GY, byIn = rem - bxl * GY;
    bx = xcd * TPEX + bxl;
    by = sc * GY + byIn;
}

// ---------------- router: scores_t [B][E][S] = softmax over E ----------------
__global__ __launch_bounds__(64)
void router_kernel(const float* __restrict__ x, const float* __restrict__ rw,
                   float* __restrict__ scores) {
    int token = blockIdx.x;
    int lane  = threadIdx.x;
    const float4* xr = reinterpret_cast<const float4*>(x + (size_t)token * DIMD);
    float4 xv[4];
#pragma unroll
    for (int j = 0; j < 4; ++j) xv[j] = xr[lane * 4 + j];
    float acc[NEXP];
#pragma unroll
    for (int e = 0; e < NEXP; ++e) {
        const float4* wr = reinterpret_cast<const float4*>(rw + (size_t)e * DIMD);
        float a = 0.f;
#pragma unroll
        for (int j = 0; j < 4; ++j) {
            float4 wv = wr[lane * 4 + j];
            a += xv[j].x * wv.x; a += xv[j].y * wv.y;
            a += xv[j].z * wv.z; a += xv[j].w * wv.w;
        }
#pragma unroll
        for (int off = 32; off > 0; off >>= 1) a += __shfl_xor(a, off);
        acc[e] = a;
    }
    float m = acc[0];
#pragma unroll
    for (int e = 1; e < NEXP; ++e) m = fmaxf(m, acc[e]);
    float s = 0.f;
#pragma unroll
    for (int e = 0; e < NEXP; ++e) { acc[e] = expf(acc[e] - m); s += acc[e]; }
    float inv = 1.f / s;
    if (lane == 0) {
        int b = token >> 11;
        int t = token & (SEQ - 1);
#pragma unroll
        for (int e = 0; e < NEXP; ++e)
            scores[((size_t)(b * NEXP + e)) * SEQ + t] = acc[e] * inv;
    }
}

// ------- expert-choice top-k via exact rank (stable, desc), 256 blocks -------
__global__ __launch_bounds__(256)
void topk_kernel(const float* __restrict__ scores, int* __restrict__ sel,
                 float* __restrict__ gate, int* __restrict__ cnt,
                 int* __restrict__ invmap) {
    int be    = blockIdx.x >> 3;
    int chunk = blockIdx.x & 7;
    const float* sc = scores + (size_t)be * SEQ;
    __shared__ float s_sc[SEQ];
    int t = threadIdx.x;
#pragma unroll
    for (int q = 0; q < 8; ++q) s_sc[t + q * 256] = sc[t + q * 256];
    __syncthreads();
    int i = chunk * 256 + t;
    float v = s_sc[i];
    int r = 0;
#pragma unroll 8
    for (int j = 0; j < SEQ; ++j) {
        float u = s_sc[j];
        r += (u > v) || (u == v && j < i);
    }
    if (r < CAPC) {
        sel [(size_t)be * CAPC + r] = i;
        gate[(size_t)be * CAPC + r] = v;
        int b = be >> 3, e = be & 7;
        int tok = b * SEQ + i;
        int p = atomicAdd(cnt + tok, 1);
        invmap[(size_t)tok * 8 + p] = e * RPEX + b * CAPC + r;   // Y row
    }
}

// ---------------- gather: A1 rows (padded) -> bf16 ---------------------------
__global__ __launch_bounds__(256)
void gather_kernel(const float* __restrict__ x, const int* __restrict__ sel,
                   unsigned short* __restrict__ dhi) {
    int gr = blockIdx.x;
    int e  = gr / RPEX;
    int rl = gr - e * RPEX;
    int t  = threadIdx.x;
    size_t dbase = (size_t)gr * DIMD + t * 4;
    if (rl < BATCH * CAPC) {
        int b = rl / CAPC, c = rl - b * CAPC;
        int tok = sel[(size_t)(b * NEXP + e) * CAPC + c];
        float4 v = *reinterpret_cast<const float4*>(x + ((size_t)(b * SEQ + tok)) * DIMD + t * 4);
        ushort4 h;
        h.x = f2bf(v.x); h.y = f2bf(v.y); h.z = f2bf(v.z); h.w = f2bf(v.w);
        *reinterpret_cast<ushort4*>(dhi + dbase) = h;
    } else {
        ushort4 z = {0, 0, 0, 0};
        *reinterpret_cast<ushort4*>(dhi + dbase) = z;
    }
}

// ------ weight transpose of a sub-block: src[k0+kLen][n0+nLen] -> [n][k] bf16 -
__global__ __launch_bounds__(256)
void convT_kernel(const float* __restrict__ src, unsigned short* __restrict__ dhi,
                  int Nsrc, size_t srcEStride, int k0, int n0, int kLen, int nLen) {
    int e = blockIdx.z;
    src += (size_t)e * srcEStride;
    dhi += (size_t)e * kLen * nLen;
    int kb = blockIdx.x * 64, nb = blockIdx.y * 64;
    __shared__ float T[64][65];
    int t = threadIdx.x;
    for (int i = t; i < 1024; i += 256) {
        int r = i >> 4, c4 = (i & 15) * 4;
        float4 v = *reinterpret_cast<const float4*>(
            src + (size_t)(k0 + kb + r) * Nsrc + n0 + nb + c4);
        T[r][c4 + 0] = v.x; T[r][c4 + 1] = v.y; T[r][c4 + 2] = v.z; T[r][c4 + 3] = v.w;
    }
    __syncthreads();
    for (int i = t; i < 1024; i += 256) {
        int n = i >> 4, kc = (i & 15) * 4;
        ushort4 h;
        h.x = f2bf(T[kc + 0][n]); h.y = f2bf(T[kc + 1][n]);
        h.z = f2bf(T[kc + 2][n]); h.w = f2bf(T[kc + 3][n]);
        *reinterpret_cast<ushort4*>(dhi + (size_t)(nb + n) * kLen + kb + kc) = h;
    }
}

// ==================== single-pass bf16 MFMA GEMMs ============================
// Tile 128x128, BK=32, 256 thr (4 waves, 64x64 each, 4x4 frags 16x16x32).
// LDS rows padded to 40 ushorts (80 B); 20 KB total.
#define GEMM_STAGE_DECLS \
    __shared__ __align__(16) unsigned short As_h[128][40]; \
    __shared__ __align__(16) unsigned short Bs_h[128][40];

__device__ __forceinline__ void mfma_single(f32x4 acc[4][4], const bf16x8 ah[4],
                                            const bf16x8 bh[4]) {
#pragma unroll
    for (int m = 0; m < 4; ++m)
#pragma unroll
        for (int n = 0; n < 4; ++n)
            acc[m][n] = __builtin_amdgcn_mfma_f32_16x16x32_bf16(ah[m], bh[n], acc[m][n], 0, 0, 0);
}

#define LOADK1(k0c) do { \
    rAh0 = *(const uint4*)(Ahi + a0 + (k0c) + kc0); rAh1 = *(const uint4*)(Ahi + a1 + (k0c) + kc0); \
    rBh0 = *(const uint4*)(Bh  + b0 + (k0c) + kc0); rBh1 = *(const uint4*)(Bh  + b1o + (k0c) + kc0); } while (0)

#define STAGEK1() do { \
    *(uint4*)&As_h[srow][kc0] = rAh0; *(uint4*)&As_h[srow + 64][kc0] = rAh1; \
    *(uint4*)&Bs_h[srow][kc0] = rBh0; *(uint4*)&Bs_h[srow + 64][kc0] = rBh1; } while (0)

#define FRAG_READS() \
    bf16x8 ah[4], bh[4]; \
    _Pragma("unroll") \
    for (int m = 0; m < 4; ++m) \
        ah[m] = *(const bf16x8*)&As_h[wr * 64 + m * 16 + li][grp * 8]; \
    _Pragma("unroll") \
    for (int n = 0; n < 4; ++n) \
        bh[n] = *(const bf16x8*)&Bs_h[wc * 64 + n * 16 + li][grp * 8];

// -------- GEMM1: H[:,chunk] = gelu(A1 @ W1c^T + b1[nbias0+...]), K=1024 ------
__global__ __launch_bounds__(256)
void gemm1_mfma(const unsigned short* __restrict__ Ahi,
                const unsigned short* __restrict__ Whi,
                const float* __restrict__ bias, unsigned short* __restrict__ Hhi,
                size_t wstride, int nbias0, int ldh, int GY) {
    const int K = DIMD;
    int bx, by; swz_grp(GY, bx, by);
    int bn = by * 128;
    int e = bx / TPEX;
    const unsigned short* Bh = Whi + (size_t)e * wstride;
    int t = threadIdx.x;
    int l = t & 63, wid = t >> 6;
    int wr = wid >> 1, wc = wid & 1;
    int grp = l >> 4, li = l & 15;

    GEMM_STAGE_DECLS

    int srow = t >> 2, scg = t & 3, kc0 = scg * 8;
    size_t a0 = (size_t)(bx * 128 + srow) * K;
    size_t a1 = (size_t)(bx * 128 + srow + 64) * K;
    size_t b0 = (size_t)(bn + srow) * K;
    size_t b1o = (size_t)(bn + srow + 64) * K;

    f32x4 acc[4][4];
#pragma unroll
    for (int m = 0; m < 4; ++m)
#pragma unroll
        for (int n = 0; n < 4; ++n) { f32x4 z = {0.f, 0.f, 0.f, 0.f}; acc[m][n] = z; }

    uint4 rAh0, rAh1, rBh0, rBh1;
    LOADK1(0);
    for (int kt = 0; kt < K; kt += 32) {
        __syncthreads();
        STAGEK1();
        __syncthreads();
        if (kt + 32 < K) LOADK1(kt + 32);
        FRAG_READS();
        mfma_single(acc, ah, bh);
    }

    int hr0 = bx * 128 + wr * 64;
    int cb = bn + wc * 64;
#pragma unroll
    for (int m = 0; m < 4; ++m)
#pragma unroll
        for (int q = 0; q < 4; ++q) {
            int row = hr0 + m * 16 + grp * 4 + q;
#pragma unroll
            for (int n = 0; n < 4; ++n) {
                int col = cb + n * 16 + li;
                float v = acc[m][n][q] + bias[(size_t)e * HIDN + nbias0 + col];
                float g = 0.5f * v * (1.0f + erff(v * 0.70710678118654752f));
                Hhi[(size_t)row * ldh + col] = f2bf(g);
            }
        }
}

// -------- GEMM2: Y[row] (+)= gate*(Hc @ W2c^T [+ b2]) dense, no atomics ------
__global__ __launch_bounds__(256)
void gemm2_mfma(const unsigned short* __restrict__ Ahi,
                const unsigned short* __restrict__ Whi,
                const float* __restrict__ bias, const float* __restrict__ gate,
                float* __restrict__ Y, size_t wstride, int K, int GY) {
    int bx, by; swz_grp(GY, bx, by);
    int bn = by * 128;
    int e = bx / TPEX;
    int rbase_e = (bx - e * TPEX) * 128;
    const unsigned short* Bh = Whi + (size_t)e * wstride;
    int t = threadIdx.x;
    int l = t & 63, wid = t >> 6;
    int wr = wid >> 1, wc = wid & 1;
    int grp = l >> 4, li = l & 15;

    GEMM_STAGE_DECLS

    int srow = t >> 2, scg = t & 3, kc0 = scg * 8;
    size_t a0 = (size_t)(bx * 128 + srow) * K;
    size_t a1 = (size_t)(bx * 128 + srow + 64) * K;
    size_t b0 = (size_t)(bn + srow) * K;
    size_t b1o = (size_t)(bn + srow + 64) * K;

    f32x4 acc[4][4];
#pragma unroll
    for (int m = 0; m < 4; ++m)
#pragma unroll
        for (int n = 0; n < 4; ++n) { f32x4 z = {0.f, 0.f, 0.f, 0.f}; acc[m][n] = z; }

    uint4 rAh0, rAh1, rBh0, rBh1;
    LOADK1(0);
    for (int kt = 0; kt < K; kt += 32) {
        __syncthreads();
        STAGEK1();
        __syncthreads();
        if (kt + 32 < K) LOADK1(kt + 32);
        FRAG_READS();
        mfma_single(acc, ah, bh);
    }

    int cb = bn + wc * 64;
#pragma unroll
    for (int m = 0; m < 4; ++m)
#pragma unroll
        for (int q = 0; q < 4; ++q) {
            int off = wr * 64 + m * 16 + grp * 4 + q;
            int rloc = rbase_e + off;
            if (rloc < BATCH * CAPC) {
                int b = rloc / CAPC, c = rloc - b * CAPC;
                float g = gate[(size_t)(b * NEXP + e) * CAPC + c];
                size_t grow = (size_t)bx * 128 + off;
#pragma unroll
                for (int n = 0; n < 4; ++n) {
                    int col = cb + n * 16 + li;
                    float v = acc[m][n][q];
                    size_t yo = grow * DIMD + col;
                    if (bias) Y[yo] = g * (v + bias[(size_t)e * DIMD + col]);
                    else      Y[yo] = Y[yo] + g * v;
                }
            }
        }
}

// -------- combine: out[b,s,:] = sum over <=8 gated Y rows (no atomics) -------
__global__ __launch_bounds__(64)
void combine_kernel(const float* __restrict__ Y, const int* __restrict__ cnt,
                    const int* __restrict__ invmap, float* __restrict__ out) {
    int tok = blockIdx.x;
    int lane = threadIdx.x;
    int n = cnt[tok];
    f32x4 acc[4];
#pragma unroll
    for (int q = 0; q < 4; ++q) { f32x4 z = {0.f, 0.f, 0.f, 0.f}; acc[q] = z; }
#pragma unroll
    for (int j = 0; j < 8; ++j) {
        if (j < n) {
            int row = invmap[(size_t)tok * 8 + j];
            const f32x4* yr = reinterpret_cast<const f32x4*>(Y + (size_t)row * DIMD);
#pragma unroll
            for (int q = 0; q < 4; ++q) acc[q] += yr[q * 64 + lane];
        }
    }
    f32x4* op = reinterpret_cast<f32x4*>(out + (size_t)tok * DIMD);
#pragma unroll
    for (int q = 0; q < 4; ++q) op[q * 64 + lane] = acc[q];
}

extern "C" void kernel_launch(void* const* d_in, const int* in_sizes, int n_in,
                              void* d_out, int out_size, void* d_ws, size_t ws_size,
                              hipStream_t stream) {
    (void)in_sizes; (void)n_in; (void)out_size;
    const float* x  = (const float*)d_in[0];
    const float* rw = (const float*)d_in[1];
    const float* w1 = (const float*)d_in[2];
    const float* b1 = (const float*)d_in[3];
    const float* w2 = (const float*)d_in[4];
    const float* b2 = (const float*)d_in[5];
    float* out = (float*)d_out;

    char* ws = (char*)d_ws;
    size_t off = 0;
    auto alloc = [&](size_t bytes) -> char* {
        char* p = ws + off;
        off = (off + bytes + 255) & ~(size_t)255;
        return p;
    };

    float* scores = (float*)alloc((size_t)BATCH * NEXP * SEQ * 4);
    int*   sel    = (int*)  alloc((size_t)BATCH * NEXP * CAPC * 4);
    float* gate   = (float*)alloc((size_t)BATCH * NEXP * CAPC * 4);
    int*   cnt    = (int*)  alloc((size_t)BATCH * SEQ * 4);
    int*   invmap = (int*)  alloc((size_t)BATCH * SEQ * 8 * 4);
    float* Y      = (float*)alloc((size_t)MTOT * DIMD * 4);
    size_t common = off;

    // ---- choose N-chunk factor C: footprint = common + A1 + (134+143)/C MB --
    const size_t A1B = (size_t)MTOT * DIMD * 2;          // A1 bf16
    int C = 8;
    for (int c = 1; c <= 8; c <<= 1) {
        size_t wc = (size_t)NEXP * (HIDN / c) * DIMD * 2;   // one of 2 W arrays
        size_t hc = (size_t)MTOT * (HIDN / c) * 2;          // H bf16
        size_t need = common + A1B + 2 * wc + hc + (8u << 20);
        if (need <= ws_size) { C = c; break; }
    }
    const int HN = HIDN / C;
    const int nY1 = HN / 128;
    const int GY1 = (nY1 < 8) ? nY1 : 8;

    unsigned short* A1h = (unsigned short*)alloc(A1B);
    size_t WCB = (size_t)NEXP * HN * DIMD * 2;
    size_t HCB = (size_t)MTOT * HN * 2;
    unsigned short* W1h = (unsigned short*)alloc(WCB);
    unsigned short* W2h = (unsigned short*)alloc(WCB);
    unsigned short* Hh  = (unsigned short*)alloc(HCB);

    hipMemsetAsync(cnt, 0, (size_t)BATCH * SEQ * 4, stream);
    router_kernel<<<BATCH * SEQ, 64, 0, stream>>>(x, rw, scores);
    topk_kernel<<<BATCH * NEXP * 8, 256, 0, stream>>>(scores, sel, gate, cnt, invmap);
    gather_kernel<<<MTOT, 256, 0, stream>>>(x, sel, A1h);

    for (int c = 0; c < C; ++c) {
        convT_kernel<<<dim3(DIMD / 64, HN / 64, NEXP), 256, 0, stream>>>(
            w1, W1h, HIDN, (size_t)DIMD * HIDN, 0, c * HN, DIMD, HN);
        gemm1_mfma<<<MTILES * nY1, 256, 0, stream>>>(
            A1h, W1h, b1, Hh, (size_t)HN * DIMD, c * HN, HN, GY1);
        convT_kernel<<<dim3(HN / 64, DIMD / 64, NEXP), 256, 0, stream>>>(
            w2, W2h, DIMD, (size_t)HIDN * DIMD, c * HN, 0, HN, DIMD);
        gemm2_mfma<<<MTILES * (DIMD / 128), 256, 0, stream>>>(
            Hh, W2h, (c == 0) ? b2 : nullptr, gate, Y,
            (size_t)DIMD * HN, HN, 4);
    }
    combine_kernel<<<BATCH * SEQ, 64, 0, stream>>>(Y, cnt, invmap, out);
}

// Round 8
// 650.895 us; speedup vs baseline: 12.6835x; 1.0555x over previous
//
#include <hip/hip_runtime.h>
#include <cstdint>

#define DIMD  1024
#define NEXP  8
#define HIDN  4096
#define BATCH 4
#define SEQ   2048
#define CAPC  513                  // int(2048*2.0/8)+1
#define RPEX  2176                 // rows per expert, padded to 17*128
#define TPEX  17                   // 128-row tiles per expert
#define MTOT  (NEXP * RPEX)        // 17408
#define MTILES (MTOT / 128)        // 136

typedef __bf16 bf16x8 __attribute__((ext_vector_type(8)));
typedef float  f32x4  __attribute__((ext_vector_type(4)));

__device__ __forceinline__ unsigned short f2bf(float f) {
    unsigned u = __float_as_uint(f);
    unsigned r = (u + 0x7FFFu + ((u >> 16) & 1u)) >> 16;
    return (unsigned short)r;
}

// async 16B global->LDS (direct DMA, no VGPR round-trip). LDS dest is
// wave-uniform base + lane*16.
__device__ __forceinline__ void gl16(const unsigned short* g, unsigned short* l) {
    __builtin_amdgcn_global_load_lds(
        (const __attribute__((address_space(1))) void*)g,
        (__attribute__((address_space(3))) void*)l, 16, 0, 0);
}

// Within-XCD supercolumn traversal. Grid = 136 * nY, 136 = 8 XCDs * 17 bx.
__device__ __forceinline__ void swz_grp(int GY, int& bx, int& by) {
    int xcd = blockIdx.x & 7, pos = blockIdx.x >> 3;
    int tps = TPEX * GY;
    int sc = pos / tps, rem = pos - sc * tps;
    int bxl = rem / GY, byIn = rem - bxl * GY;
    bx = xcd * TPEX + bxl;
    by = sc * GY + byIn;
}

// ---------------- router: scores_t [B][E][S] = softmax over E ----------------
__global__ __launch_bounds__(64)
void router_kernel(const float* __restrict__ x, const float* __restrict__ rw,
                   float* __restrict__ scores) {
    int token = blockIdx.x;
    int lane  = threadIdx.x;
    const float4* xr = reinterpret_cast<const float4*>(x + (size_t)token * DIMD);
    float4 xv[4];
#pragma unroll
    for (int j = 0; j < 4; ++j) xv[j] = xr[lane * 4 + j];
    float acc[NEXP];
#pragma unroll
    for (int e = 0; e < NEXP; ++e) {
        const float4* wr = reinterpret_cast<const float4*>(rw + (size_t)e * DIMD);
        float a = 0.f;
#pragma unroll
        for (int j = 0; j < 4; ++j) {
            float4 wv = wr[lane * 4 + j];
            a += xv[j].x * wv.x; a += xv[j].y * wv.y;
            a += xv[j].z * wv.z; a += xv[j].w * wv.w;
        }
#pragma unroll
        for (int off = 32; off > 0; off >>= 1) a += __shfl_xor(a, off);
        acc[e] = a;
    }
    float m = acc[0];
#pragma unroll
    for (int e = 1; e < NEXP; ++e) m = fmaxf(m, acc[e]);
    float s = 0.f;
#pragma unroll
    for (int e = 0; e < NEXP; ++e) { acc[e] = expf(acc[e] - m); s += acc[e]; }
    float inv = 1.f / s;
    if (lane == 0) {
        int b = token >> 11;
        int t = token & (SEQ - 1);
#pragma unroll
        for (int e = 0; e < NEXP; ++e)
            scores[((size_t)(b * NEXP + e)) * SEQ + t] = acc[e] * inv;
    }
}

// ------- expert-choice top-k via exact rank (stable, desc), 256 blocks -------
__global__ __launch_bounds__(256)
void topk_kernel(const float* __restrict__ scores, int* __restrict__ sel,
                 float* __restrict__ gate, int* __restrict__ cnt,
                 int* __restrict__ invmap) {
    int be    = blockIdx.x >> 3;
    int chunk = blockIdx.x & 7;
    const float* sc = scores + (size_t)be * SEQ;
    __shared__ float s_sc[SEQ];
    int t = threadIdx.x;
#pragma unroll
    for (int q = 0; q < 8; ++q) s_sc[t + q * 256] = sc[t + q * 256];
    __syncthreads();
    int i = chunk * 256 + t;
    float v = s_sc[i];
    int r = 0;
#pragma unroll 8
    for (int j = 0; j < SEQ; ++j) {
        float u = s_sc[j];
        r += (u > v) || (u == v && j < i);
    }
    if (r < CAPC) {
        sel [(size_t)be * CAPC + r] = i;
        gate[(size_t)be * CAPC + r] = v;
        int b = be >> 3, e = be & 7;
        int tok = b * SEQ + i;
        int p = atomicAdd(cnt + tok, 1);
        invmap[(size_t)tok * 8 + p] = e * RPEX + b * CAPC + r;   // Y row
    }
}

// ---------------- gather: A1 rows (padded) -> bf16 ---------------------------
__global__ __launch_bounds__(256)
void gather_kernel(const float* __restrict__ x, const int* __restrict__ sel,
                   unsigned short* __restrict__ dhi) {
    int gr = blockIdx.x;
    int e  = gr / RPEX;
    int rl = gr - e * RPEX;
    int t  = threadIdx.x;
    size_t dbase = (size_t)gr * DIMD + t * 4;
    if (rl < BATCH * CAPC) {
        int b = rl / CAPC, c = rl - b * CAPC;
        int tok = sel[(size_t)(b * NEXP + e) * CAPC + c];
        float4 v = *reinterpret_cast<const float4*>(x + ((size_t)(b * SEQ + tok)) * DIMD + t * 4);
        ushort4 h;
        h.x = f2bf(v.x); h.y = f2bf(v.y); h.z = f2bf(v.z); h.w = f2bf(v.w);
        *reinterpret_cast<ushort4*>(dhi + dbase) = h;
    } else {
        ushort4 z = {0, 0, 0, 0};
        *reinterpret_cast<ushort4*>(dhi + dbase) = z;
    }
}

// ------ weight transpose of a sub-block: src[k0+kLen][n0+nLen] -> [n][k] bf16 -
__global__ __launch_bounds__(256)
void convT_kernel(const float* __restrict__ src, unsigned short* __restrict__ dhi,
                  int Nsrc, size_t srcEStride, int k0, int n0, int kLen, int nLen) {
    int e = blockIdx.z;
    src += (size_t)e * srcEStride;
    dhi += (size_t)e * kLen * nLen;
    int kb = blockIdx.x * 64, nb = blockIdx.y * 64;
    __shared__ float T[64][65];
    int t = threadIdx.x;
    for (int i = t; i < 1024; i += 256) {
        int r = i >> 4, c4 = (i & 15) * 4;
        float4 v = *reinterpret_cast<const float4*>(
            src + (size_t)(k0 + kb + r) * Nsrc + n0 + nb + c4);
        T[r][c4 + 0] = v.x; T[r][c4 + 1] = v.y; T[r][c4 + 2] = v.z; T[r][c4 + 3] = v.w;
    }
    __syncthreads();
    for (int i = t; i < 1024; i += 256) {
        int n = i >> 4, kc = (i & 15) * 4;
        ushort4 h;
        h.x = f2bf(T[kc + 0][n]); h.y = f2bf(T[kc + 1][n]);
        h.z = f2bf(T[kc + 2][n]); h.w = f2bf(T[kc + 3][n]);
        *reinterpret_cast<ushort4*>(dhi + (size_t)(nb + n) * kLen + kb + kc) = h;
    }
}

// ============ single-pass bf16 MFMA GEMMs, global_load_lds + XOR swizzle =====
// Tile 128x128, BK=32, 256 thr (4 waves, 64x64 each, 4x4 frags 16x16x32).
// LDS [2 buf][128][32] ushort per matrix (8KB each, 32KB total), LINEAR layout
// (global_load_lds requires it). Swizzle done by permuting the GLOBAL source
// chunk per lane (stage) and the read column (frags) with the same involution:
//   chunk col g at row r lives at LDS col g ^ ((r>>1)&3).  (rule #21)
// Bank starts for 8 consecutive rows: {0,16,4,20,8,24,12,28} -> 2-way = free.

#define GEMM_PRE(Abase, Bbase, Kc)                                              \
    int t = threadIdx.x;                                                        \
    int l = t & 63, wid = t >> 6;                                               \
    int wr = wid >> 1, wc = wid & 1;                                            \
    int grp = l >> 4, li = l & 15;                                              \
    int fsw  = (grp ^ ((li >> 1) & 3)) * 8;      /* frag-read swizzled col */   \
    int gsrc = ((l & 3) ^ ((l >> 3) & 3)) * 8;   /* stage source chunk col */   \
    int ra0 = (wid * 2) * 16 + (l >> 2);         /* staging rows (2 regions) */ \
    int ra1 = ra0 + 16;                                                         \
    __shared__ __align__(16) unsigned short As[2][4096];                        \
    __shared__ __align__(16) unsigned short Bs[2][4096];                        \
    int regA = wid * 1024;                       /* ushort offset, 2x512 */     \
    const unsigned short* gA0 = (Abase) + (size_t)(bx * 128 + ra0) * (Kc) + gsrc; \
    const unsigned short* gA1 = (Abase) + (size_t)(bx * 128 + ra1) * (Kc) + gsrc; \
    const unsigned short* gB0 = (Bbase) + (size_t)(bn + ra0) * (Kc) + gsrc;     \
    const unsigned short* gB1 = (Bbase) + (size_t)(bn + ra1) * (Kc) + gsrc;     \
    f32x4 acc[4][4];                                                            \
    _Pragma("unroll")                                                           \
    for (int m = 0; m < 4; ++m)                                                 \
        _Pragma("unroll")                                                       \
        for (int n = 0; n < 4; ++n) { f32x4 z = {0.f,0.f,0.f,0.f}; acc[m][n] = z; }

#define STAGE(buf, kt) do {                                                     \
    gl16(gA0 + (kt), &As[buf][regA]);                                           \
    gl16(gA1 + (kt), &As[buf][regA + 512]);                                     \
    gl16(gB0 + (kt), &Bs[buf][regA]);                                           \
    gl16(gB1 + (kt), &Bs[buf][regA + 512]); } while (0)

#define GEMM_LOOP(Kc) do {                                                      \
    STAGE(0, 0);                                                                \
    __syncthreads();                                                            \
    int cur = 0;                                                                \
    for (int kt = 0; kt < (Kc); kt += 32) {                                     \
        if (kt + 32 < (Kc)) STAGE(cur ^ 1, kt + 32);                            \
        bf16x8 ah[4], bh[4];                                                    \
        const unsigned short* aB = &As[cur][wr * 2048 + li * 32 + fsw];         \
        const unsigned short* bB = &Bs[cur][wc * 2048 + li * 32 + fsw];         \
        ah[0] = *(const bf16x8*)(aB);        ah[1] = *(const bf16x8*)(aB + 512); \
        ah[2] = *(const bf16x8*)(aB + 1024); ah[3] = *(const bf16x8*)(aB + 1536); \
        bh[0] = *(const bf16x8*)(bB);        bh[1] = *(const bf16x8*)(bB + 512); \
        bh[2] = *(const bf16x8*)(bB + 1024); bh[3] = *(const bf16x8*)(bB + 1536); \
        _Pragma("unroll")                                                       \
        for (int m = 0; m < 4; ++m)                                             \
            _Pragma("unroll")                                                   \
            for (int n = 0; n < 4; ++n)                                         \
                acc[m][n] = __builtin_amdgcn_mfma_f32_16x16x32_bf16(            \
                    ah[m], bh[n], acc[m][n], 0, 0, 0);                          \
        __syncthreads();                                                        \
        cur ^= 1;                                                               \
    } } while (0)

// -------- GEMM1: H[:,chunk] = gelu(A1 @ W1c^T + b1[nbias0+...]), K=1024 ------
__global__ __launch_bounds__(256)
void gemm1_mfma(const unsigned short* __restrict__ Ahi,
                const unsigned short* __restrict__ Whi,
                const float* __restrict__ bias, unsigned short* __restrict__ Hhi,
                size_t wstride, int nbias0, int ldh, int GY) {
    const int K = DIMD;
    int bx, by; swz_grp(GY, bx, by);
    int bn = by * 128;
    int e = bx / TPEX;
    const unsigned short* Bh = Whi + (size_t)e * wstride;

    GEMM_PRE(Ahi, Bh, K)
    GEMM_LOOP(K);

    int hr0 = bx * 128 + wr * 64;
    int cb = bn + wc * 64;
#pragma unroll
    for (int m = 0; m < 4; ++m)
#pragma unroll
        for (int q = 0; q < 4; ++q) {
            int row = hr0 + m * 16 + grp * 4 + q;
#pragma unroll
            for (int n = 0; n < 4; ++n) {
                int col = cb + n * 16 + li;
                float v = acc[m][n][q] + bias[(size_t)e * HIDN + nbias0 + col];
                float g = 0.5f * v * (1.0f + erff(v * 0.70710678118654752f));
                Hhi[(size_t)row * ldh + col] = f2bf(g);
            }
        }
}

// -------- GEMM2: Y[row] (+)= gate*(Hc @ W2c^T [+ b2]) dense, no atomics ------
__global__ __launch_bounds__(256)
void gemm2_mfma(const unsigned short* __restrict__ Ahi,
                const unsigned short* __restrict__ Whi,
                const float* __restrict__ bias, const float* __restrict__ gate,
                float* __restrict__ Y, size_t wstride, int K, int GY) {
    int bx, by; swz_grp(GY, bx, by);
    int bn = by * 128;
    int e = bx / TPEX;
    int rbase_e = (bx - e * TPEX) * 128;
    const unsigned short* Bh = Whi + (size_t)e * wstride;

    GEMM_PRE(Ahi, Bh, K)
    GEMM_LOOP(K);

    int cb = bn + wc * 64;
#pragma unroll
    for (int m = 0; m < 4; ++m)
#pragma unroll
        for (int q = 0; q < 4; ++q) {
            int off = wr * 64 + m * 16 + grp * 4 + q;
            int rloc = rbase_e + off;
            if (rloc < BATCH * CAPC) {
                int b = rloc / CAPC, c = rloc - b * CAPC;
                float g = gate[(size_t)(b * NEXP + e) * CAPC + c];
                size_t grow = (size_t)bx * 128 + off;
#pragma unroll
                for (int n = 0; n < 4; ++n) {
                    int col = cb + n * 16 + li;
                    float v = acc[m][n][q];
                    size_t yo = grow * DIMD + col;
                    if (bias) Y[yo] = g * (v + bias[(size_t)e * DIMD + col]);
                    else      Y[yo] = Y[yo] + g * v;
                }
            }
        }
}

// -------- combine: out[b,s,:] = sum over <=8 gated Y rows (no atomics) -------
__global__ __launch_bounds__(64)
void combine_kernel(const float* __restrict__ Y, const int* __restrict__ cnt,
                    const int* __restrict__ invmap, float* __restrict__ out) {
    int tok = blockIdx.x;
    int lane = threadIdx.x;
    int n = cnt[tok];
    f32x4 acc[4];
#pragma unroll
    for (int q = 0; q < 4; ++q) { f32x4 z = {0.f, 0.f, 0.f, 0.f}; acc[q] = z; }
#pragma unroll
    for (int j = 0; j < 8; ++j) {
        if (j < n) {
            int row = invmap[(size_t)tok * 8 + j];
            const f32x4* yr = reinterpret_cast<const f32x4*>(Y + (size_t)row * DIMD);
#pragma unroll
            for (int q = 0; q < 4; ++q) acc[q] += yr[q * 64 + lane];
        }
    }
    f32x4* op = reinterpret_cast<f32x4*>(out + (size_t)tok * DIMD);
#pragma unroll
    for (int q = 0; q < 4; ++q) op[q * 64 + lane] = acc[q];
}

extern "C" void kernel_launch(void* const* d_in, const int* in_sizes, int n_in,
                              void* d_out, int out_size, void* d_ws, size_t ws_size,
                              hipStream_t stream) {
    (void)in_sizes; (void)n_in; (void)out_size;
    const float* x  = (const float*)d_in[0];
    const float* rw = (const float*)d_in[1];
    const float* w1 = (const float*)d_in[2];
    const float* b1 = (const float*)d_in[3];
    const float* w2 = (const float*)d_in[4];
    const float* b2 = (const float*)d_in[5];
    float* out = (float*)d_out;

    char* ws = (char*)d_ws;
    size_t off = 0;
    auto alloc = [&](size_t bytes) -> char* {
        char* p = ws + off;
        off = (off + bytes + 255) & ~(size_t)255;
        return p;
    };

    float* scores = (float*)alloc((size_t)BATCH * NEXP * SEQ * 4);
    int*   sel    = (int*)  alloc((size_t)BATCH * NEXP * CAPC * 4);
    float* gate   = (float*)alloc((size_t)BATCH * NEXP * CAPC * 4);
    int*   cnt    = (int*)  alloc((size_t)BATCH * SEQ * 4);
    int*   invmap = (int*)  alloc((size_t)BATCH * SEQ * 8 * 4);
    float* Y      = (float*)alloc((size_t)MTOT * DIMD * 4);
    size_t common = off;

    // ---- choose N-chunk factor C: footprint = common + A1 + (134+143)/C MB --
    const size_t A1B = (size_t)MTOT * DIMD * 2;          // A1 bf16
    int C = 8;
    for (int c = 1; c <= 8; c <<= 1) {
        size_t wc = (size_t)NEXP * (HIDN / c) * DIMD * 2;   // one of 2 W arrays
        size_t hc = (size_t)MTOT * (HIDN / c) * 2;          // H bf16
        size_t need = common + A1B + 2 * wc + hc + (8u << 20);
        if (need <= ws_size) { C = c; break; }
    }
    const int HN = HIDN / C;
    const int nY1 = HN / 128;
    const int GY1 = (nY1 < 8) ? nY1 : 8;

    unsigned short* A1h = (unsigned short*)alloc(A1B);
    size_t WCB = (size_t)NEXP * HN * DIMD * 2;
    size_t HCB = (size_t)MTOT * HN * 2;
    unsigned short* W1h = (unsigned short*)alloc(WCB);
    unsigned short* W2h = (unsigned short*)alloc(WCB);
    unsigned short* Hh  = (unsigned short*)alloc(HCB);

    hipMemsetAsync(cnt, 0, (size_t)BATCH * SEQ * 4, stream);
    router_kernel<<<BATCH * SEQ, 64, 0, stream>>>(x, rw, scores);
    topk_kernel<<<BATCH * NEXP * 8, 256, 0, stream>>>(scores, sel, gate, cnt, invmap);
    gather_kernel<<<MTOT, 256, 0, stream>>>(x, sel, A1h);

    for (int c = 0; c < C; ++c) {
        convT_kernel<<<dim3(DIMD / 64, HN / 64, NEXP), 256, 0, stream>>>(
            w1, W1h, HIDN, (size_t)DIMD * HIDN, 0, c * HN, DIMD, HN);
        gemm1_mfma<<<MTILES * nY1, 256, 0, stream>>>(
            A1h, W1h, b1, Hh, (size_t)HN * DIMD, c * HN, HN, GY1);
        convT_kernel<<<dim3(HN / 64, DIMD / 64, NEXP), 256, 0, stream>>>(
            w2, W2h, DIMD, (size_t)HIDN * DIMD, c * HN, 0, HN, DIMD);
        gemm2_mfma<<<MTILES * (DIMD / 128), 256, 0, stream>>>(
            Hh, W2h, (c == 0) ? b2 : nullptr, gate, Y,
            (size_t)DIMD * HN, HN, 4);
    }
    combine_kernel<<<BATCH * SEQ, 64, 0, stream>>>(Y, cnt, invmap, out);
}